// Round 3
// baseline (12090.012 us; speedup 1.0000x reference)
//
#include <hip/hip_runtime.h>
#include <math.h>

// ---------------- dims ----------------
#define B_ 32
#define C_ 3
#define HW_ 224
#define NP_ 14
#define PS_ 16
#define S_ 197        // NP*NP + 1
#define SP_ 224       // S padded to multiple of 32 (K dim of AV)
#define D_ 768
#define NH_ 12
#define DH_ 64
#define L_ 12
#define MLP_ 3072
#define OUT_ 1000

#define BM 64
#define BN 64
#define BK 16

typedef unsigned short u16;
typedef unsigned int u32;
typedef __attribute__((ext_vector_type(8))) short short8_t;
typedef __attribute__((ext_vector_type(4))) float f32x4;
typedef const __attribute__((address_space(1))) u16 gq_t;
typedef __attribute__((address_space(3))) u16 lq_t;

// ---------------- bf16 helpers ----------------
__device__ __forceinline__ u16 f2bf(float x) {
    union { float f; u32 u; } a; a.f = x;
    u32 r = (a.u + 0x7fffu + ((a.u >> 16) & 1u)) >> 16;   // RNE
    return (u16)r;
}
__device__ __forceinline__ float bf2f(u16 h) {
    union { u32 u; float f; } a; a.u = ((u32)h) << 16; return a.f;
}

// ================= bf16x3 split MFMA GEMM (batched, split-K, 2-phase pipelined) =================
// C = A @ B^T(stored [N,K]) using hi/lo bf16 decomposition of fp32 inputs.
// 3 MFMAs per product: hi*hi + hi*lo + lo*hi  (~2^-16 relative error).
// 2-phase double-buffered LDS: issue next tile's global_load_lds BEFORE computing
// current tile; ONE __syncthreads per K-step (its vmcnt(0) drain overlaps compute).
// Per-z offsets: off = (z/div)*so + (z%div)*si  for A, B, C/O, bias.
// ksplit>1: blockIdx.z indexes a K chunk (batch must be 1); epilogue does
//           atomicAdd into C (accum semantics), bias added by chunk 0 only.
// mode 0: C[row*ldc+col] = acc + bias (+C_old if accum); remap: row=grow+grow/196+1
// mode 1: gelu(acc+bias) -> bf16 hi/lo pair at grow*ldc+col
// mode 2: (acc+bias)      -> bf16 hi/lo pair at grow*ldc+col; zero-fills cols [N,ldc)
// mode 3: (acc+bias)      -> bf16 hi/lo TRANSPOSED store:
//         idx = (grow/S_)*(DH_*SP_) + col*SP_ + grow%S_   (v^T per (head,batch))
__global__ __launch_bounds__(256) void mfma_gemm_kernel(
    const u16* __restrict__ Ahi, const u16* __restrict__ Alo,
    const u16* __restrict__ Bhi, const u16* __restrict__ Blo,
    const float* __restrict__ bias, float* __restrict__ C,
    u16* __restrict__ Ohi, u16* __restrict__ Olo,
    int M, int N, int K, int lda, int ldb, int ldc,
    int mode, int accum, int remap, int ksplit,
    int divA, long long sAo, long long sAi,
    int divB, long long sBo, long long sBi,
    int divC, long long sCo, long long sCi,
    int divBias, long long sBiaso, long long sBiasi)
{
    // chunk-major LDS: [buf][mat][k-octet][row][8 bf16] -> conflict-free b128 reads,
    // and global_load_lds lands lane L at row h*64+L (contiguous 16B/lane).
    __shared__ u16 lds[2][4][4][128][8];   // 64 KB (2 blocks/CU)

    int z = blockIdx.z;
    int kz = 0;
    if (ksplit > 1) { kz = z; z = 0; }
    long long aoff = (long long)(z / divA) * sAo + (long long)(z % divA) * sAi;
    long long boff = (long long)(z / divB) * sBo + (long long)(z % divB) * sBi;
    long long coff = (long long)(z / divC) * sCo + (long long)(z % divC) * sCi;
    long long biasoff = (long long)(z / divBias) * sBiaso + (long long)(z % divBias) * sBiasi;

    // ---- bijective XCD-chunked swizzle of the 2D grid (m204) ----
    int nwgx = gridDim.x;
    int nwg = nwgx * gridDim.y;
    int bid = blockIdx.y * nwgx + blockIdx.x;
    int xcd = bid & 7, lid = bid >> 3;
    int qq = nwg >> 3, rr8 = nwg & 7;
    int sw = ((xcd < rr8) ? xcd * (qq + 1) : rr8 * (qq + 1) + (xcd - rr8) * qq) + lid;
    int bx = sw % nwgx, by = sw / nwgx;

    int tid = threadIdx.x;
    int lane = tid & 63;
    int w = tid >> 6;                  // wave id 0..3
    int wm = (w >> 1) * 64, wn = (w & 1) * 64;
    int m0 = by * 128, n0 = bx * 128;
    int lm = lane & 15, qd = lane >> 4;

    const u16* src;
    int ld, base, rmax;
    if (w < 2) { src = ((w == 0) ? Ahi : Alo) + aoff; ld = lda; base = m0; rmax = M - 1; }
    else       { src = ((w == 2) ? Bhi : Blo) + boff; ld = ldb; base = n0; rmax = N - 1; }

    int kc = K / ksplit;
    int kbeg = kz * kc;
    int nsteps = kc / 32;

    // stage: wave w loads matrix w's 128x32 tile (8 x global_load_lds, 16B/lane)
    auto STAGE = [&](int buf, int k0) {
        int r0 = base + lane;
#pragma unroll
        for (int q = 0; q < 4; ++q) {
#pragma unroll
            for (int h = 0; h < 2; ++h) {
                int rr = r0 + h * 64;
                rr = rr > rmax ? rmax : rr;
                const u16* gp = src + (long long)rr * ld + (k0 + q * 8);
                u16* lp = &lds[buf][w][q][h * 64][0];
                __builtin_amdgcn_global_load_lds((gq_t*)gp, (lq_t*)lp, 16, 0, 0);
            }
        }
    };

    f32x4 acc[4][4];
#pragma unroll
    for (int i = 0; i < 4; ++i)
#pragma unroll
        for (int j = 0; j < 4; ++j)
            acc[i][j] = (f32x4){0.f, 0.f, 0.f, 0.f};

    STAGE(0, kbeg);
    __syncthreads();

    for (int t = 0; t < nsteps; ++t) {
        int cur = t & 1;
        if (t + 1 < nsteps) STAGE(cur ^ 1, kbeg + (t + 1) * 32);   // prefetch next tile

        short8_t ah[4], al[4], bh[4], bl[4];
#pragma unroll
        for (int i = 0; i < 4; ++i) {
            ah[i] = *(const short8_t*)&lds[cur][0][qd][wm + i * 16 + lm][0];
            al[i] = *(const short8_t*)&lds[cur][1][qd][wm + i * 16 + lm][0];
            bh[i] = *(const short8_t*)&lds[cur][2][qd][wn + i * 16 + lm][0];
            bl[i] = *(const short8_t*)&lds[cur][3][qd][wn + i * 16 + lm][0];
        }
#pragma unroll
        for (int i = 0; i < 4; ++i)
#pragma unroll
            for (int j = 0; j < 4; ++j) {
                acc[i][j] = __builtin_amdgcn_mfma_f32_16x16x32_bf16(ah[i], bh[j], acc[i][j], 0, 0, 0);
                acc[i][j] = __builtin_amdgcn_mfma_f32_16x16x32_bf16(ah[i], bl[j], acc[i][j], 0, 0, 0);
                acc[i][j] = __builtin_amdgcn_mfma_f32_16x16x32_bf16(al[i], bh[j], acc[i][j], 0, 0, 0);
            }
        // one barrier per K-step: implicit vmcnt(0) waits on the prefetch issued
        // ABOVE, which has had the whole ds_read+MFMA phase to complete.
        __syncthreads();
    }

    float* Cb = C ? C + coff : nullptr;
    u16* Ohb = Ohi ? Ohi + coff : nullptr;
    u16* Olb = Olo ? Olo + coff : nullptr;
    const float* biasb = (bias && kz == 0) ? bias + biasoff : nullptr;

    // ---- epilogue: C/D layout col=lane&15, row=quad*4+reg ----
#pragma unroll
    for (int j = 0; j < 4; ++j) {
        int col = n0 + wn + j * 16 + lm;
        bool cok = col < N;
        float bv = (cok && biasb) ? biasb[col] : 0.f;
#pragma unroll
        for (int i = 0; i < 4; ++i) {
#pragma unroll
            for (int r = 0; r < 4; ++r) {
                int grow = m0 + wm + i * 16 + qd * 4 + r;
                if (grow >= M) continue;
                float v = acc[i][j][r] + bv;
                if (mode == 2) {
                    if (col >= ldc) continue;          // never cross row stride
                    if (!cok) v = 0.f;                 // zero-fill K padding
                    u16 h = f2bf(v);
                    long long idx = (long long)grow * ldc + col;
                    Ohb[idx] = h;
                    Olb[idx] = f2bf(v - bf2f(h));
                } else if (mode == 3) {
                    if (!cok) continue;
                    int nn = grow / S_;
                    int ss = grow - nn * S_;
                    long long idx = (long long)nn * (DH_ * SP_) + (long long)col * SP_ + ss;
                    u16 h = f2bf(v);
                    Ohb[idx] = h;
                    Olb[idx] = f2bf(v - bf2f(h));
                } else if (mode == 1) {
                    if (!cok) continue;
                    v = 0.5f * v * (1.0f + erff(v * 0.70710678118654752f));
                    u16 h = f2bf(v);
                    long long idx = (long long)grow * ldc + col;
                    Ohb[idx] = h;
                    Olb[idx] = f2bf(v - bf2f(h));
                } else {
                    if (!cok) continue;
                    int orow = remap ? (grow + grow / 196 + 1) : grow;
                    long long idx = (long long)orow * ldc + col;
                    if (ksplit > 1) {
                        atomicAdd(&Cb[idx], v);        // accum semantics, nondet order
                    } else {
                        if (accum) v += Cb[idx];
                        Cb[idx] = v;
                    }
                }
            }
        }
    }
}

// ---------------- transpose + hi/lo split of fp32 weights ----------------
// in:  W [K][N] fp32 row-major;  out: Thi/Tlo [N][K] bf16
__global__ __launch_bounds__(256) void tconv_kernel(const float* __restrict__ W,
                                                    u16* __restrict__ Thi, u16* __restrict__ Tlo,
                                                    int K, int N)
{
    __shared__ float t[32][33];
    int n0 = blockIdx.x * 32, k0 = blockIdx.y * 32;
    int tc = threadIdx.x & 31, tr = threadIdx.x >> 5;   // tr in 0..7
#pragma unroll
    for (int u = 0; u < 4; ++u) {
        int kk = tr + u * 8;
        t[kk][tc] = W[(long long)(k0 + kk) * N + n0 + tc];
    }
    __syncthreads();
#pragma unroll
    for (int u = 0; u < 4; ++u) {
        int nn = tr + u * 8;
        float v = t[tc][nn];
        u16 h = f2bf(v);
        long long idx = (long long)(n0 + nn) * K + k0 + tc;
        Thi[idx] = h;
        Tlo[idx] = f2bf(v - bf2f(h));
    }
}

// ---------------- per-layer QKV weight prep ----------------
__global__ void qkvprep_kernel(const float* __restrict__ wq, const float* __restrict__ wk,
                               const float* __restrict__ wv,
                               const float* __restrict__ bq, const float* __restrict__ bk,
                               u16* __restrict__ qkh, u16* __restrict__ qkl,
                               u16* __restrict__ vth, u16* __restrict__ vtl,
                               float* __restrict__ bqk)
{
    int idx = blockIdx.x * 256 + threadIdx.x;
    if (idx < NH_ * 128 * 64) {
        int d = idx & 63, j = (idx >> 6) & 127, h = idx >> 13;
        float v = (j < 64) ? wq[((h << 6) + d) * 64 + j] : wk[((h << 6) + d) * 64 + (j & 63)];
        u16 hh = f2bf(v);
        qkh[idx] = hh; qkl[idx] = f2bf(v - bf2f(hh));
        return;
    }
    int i2 = idx - NH_ * 128 * 64;
    if (i2 < NH_ * 64 * 64) {
        int d = i2 & 63, j = (i2 >> 6) & 63, h = i2 >> 12;
        float v = wv[((h << 6) + d) * 64 + j];
        u16 hh = f2bf(v);
        vth[i2] = hh; vtl[i2] = f2bf(v - bf2f(hh));
        return;
    }
    int i3 = i2 - NH_ * 64 * 64;
    if (i3 < NH_ * 128) {
        int j = i3 & 127, h = i3 >> 7;
        bqk[i3] = (j < 64) ? bq[(h << 6) + j] : bk[(h << 6) + (j & 63)];
    }
}

// ---------------- zero fill (u32) ----------------
__global__ void zfill_kernel(u32* __restrict__ p, long long n) {
    long long i = (long long)blockIdx.x * 256 + threadIdx.x;
    if (i < n) p[i] = 0u;
}

// ================= fp32 generic batched GEMM (head only) =================
__global__ __launch_bounds__(256) void gemm_kernel(
    const float* __restrict__ A, const float* __restrict__ Bm,
    const float* __restrict__ bias, float* __restrict__ C,
    int M, int N, int K, int lda, int ldb, int ldc,
    int transB, int act, int accum,
    int divA, long long sAo, long long sAi,
    int divB, long long sBo, long long sBi,
    int divC, long long sCo, long long sCi,
    int divBias, long long sBiaso, long long sBiasi)
{
    int z = blockIdx.z;
    const float* Ab = A + (long long)(z / divA) * sAo + (long long)(z % divA) * sAi;
    const float* Bb = Bm + (long long)(z / divB) * sBo + (long long)(z % divB) * sBi;
    float* Cb = C + (long long)(z / divC) * sCo + (long long)(z % divC) * sCi;
    const float* biasb = bias ? (bias + (long long)(z / divBias) * sBiaso + (long long)(z % divBias) * sBiasi)
                              : nullptr;

    __shared__ float As[BK][BM + 4];
    __shared__ float Bs[BK][BN + 4];

    int tid = threadIdx.x;
    int tx = tid & 15, ty = tid >> 4;
    int m0 = blockIdx.y * BM, n0 = blockIdx.x * BN;

    float acc[4][4] = {};

    for (int k0 = 0; k0 < K; k0 += BK) {
        {
            int row = tid >> 2;
            int c4 = (tid & 3) * 4;
            int gm = m0 + row;
#pragma unroll
            for (int u = 0; u < 4; ++u) {
                int gk = k0 + c4 + u;
                float v = 0.f;
                if (gm < M && gk < K) v = Ab[(long long)gm * lda + gk];
                As[c4 + u][row] = v;
            }
        }
        if (!transB) {
            int row = tid >> 4;
            int c4 = (tid & 15) * 4;
            int gk = k0 + row;
#pragma unroll
            for (int u = 0; u < 4; ++u) {
                int gn = n0 + c4 + u;
                float v = 0.f;
                if (gk < K && gn < N) v = Bb[(long long)gk * ldb + gn];
                Bs[row][c4 + u] = v;
            }
        } else {
            int row = tid >> 2;
            int c4 = (tid & 3) * 4;
            int gn = n0 + row;
#pragma unroll
            for (int u = 0; u < 4; ++u) {
                int gk = k0 + c4 + u;
                float v = 0.f;
                if (gn < N && gk < K) v = Bb[(long long)gn * ldb + gk];
                Bs[c4 + u][row] = v;
            }
        }
        __syncthreads();
#pragma unroll
        for (int kk = 0; kk < BK; ++kk) {
            float a[4], b[4];
#pragma unroll
            for (int i = 0; i < 4; ++i) a[i] = As[kk][ty * 4 + i];
#pragma unroll
            for (int j = 0; j < 4; ++j) b[j] = Bs[kk][tx * 4 + j];
#pragma unroll
            for (int i = 0; i < 4; ++i)
#pragma unroll
                for (int j = 0; j < 4; ++j)
                    acc[i][j] += a[i] * b[j];
        }
        __syncthreads();
    }

#pragma unroll
    for (int i = 0; i < 4; ++i) {
        int gm = m0 + ty * 4 + i;
        if (gm >= M) continue;
#pragma unroll
        for (int j = 0; j < 4; ++j) {
            int gn = n0 + tx * 4 + j;
            if (gn >= N) continue;
            float v = acc[i][j];
            if (biasb) v += biasb[gn];
            if (act == 1) v = 0.5f * v * (1.0f + erff(v * 0.70710678118654752f));
            long long idx = (long long)gm * ldc + gn;
            if (accum) v += Cb[idx];
            Cb[idx] = v;
        }
    }
}

// ---------------- positional embedding ----------------
__global__ void posemb_kernel(float* __restrict__ pos) {
    int idx = blockIdx.x * 256 + threadIdx.x;
    if (idx >= S_ * D_) return;
    int s = idx / D_, d = idx % D_;
    float jj = (float)(d & ~1);
    float freq = powf(10000.0f, jj / (float)D_);
    float arg = (float)s / freq;
    pos[idx] = (d & 1) ? cosf(arg) : sinf(arg);
}

// ---------------- patchify (writes bf16 hi/lo) ----------------
__global__ void patchify_split_kernel(const float* __restrict__ x,
                                      u16* __restrict__ phi, u16* __restrict__ plo) {
    int idx = blockIdx.x * 256 + threadIdx.x;
    if (idx >= B_ * NP_ * NP_ * 768) return;
    int k = idx % 768;
    int p = (idx / 768) % (NP_ * NP_);
    int n = idx / (768 * NP_ * NP_);
    int c = k >> 8;
    int rem = k & 255;
    int a = rem >> 4;
    int b = rem & 15;
    int i = p / NP_, j = p % NP_;
    float v = x[(((long long)n * C_ + c) * HW_ + (i * PS_ + a)) * HW_ + (j * PS_ + b)];
    u16 h = f2bf(v);
    phi[idx] = h;
    plo[idx] = f2bf(v - bf2f(h));
}

// ---------------- cls token + pos emb ----------------
__global__ void addpos_kernel(float* __restrict__ tok, const float* __restrict__ pos,
                              const float* __restrict__ cls) {
    int idx = blockIdx.x * 256 + threadIdx.x;
    if (idx >= B_ * S_ * D_) return;
    int r = idx % (S_ * D_);
    int s = r / D_, d = r % D_;
    if (s == 0) tok[idx] = cls[d] + pos[d];
    else tok[idx] += pos[r];
}

// ---------------- layernorm bf16 hi/lo out ----------------
__global__ __launch_bounds__(256) void ln_split_kernel(const float* __restrict__ x,
                                                       u16* __restrict__ yhi, u16* __restrict__ ylo,
                                                       const float* __restrict__ g, const float* __restrict__ b) {
    int row = blockIdx.x;
    const float* xr = x + (long long)row * D_;
    u16* yh = yhi + (long long)row * D_;
    u16* yl = ylo + (long long)row * D_;
    int tid = threadIdx.x;
    float v[3];
    float s = 0.f;
#pragma unroll
    for (int u = 0; u < 3; ++u) { v[u] = xr[tid + 256 * u]; s += v[u]; }
    __shared__ float red[256];
    red[tid] = s; __syncthreads();
    for (int off = 128; off > 0; off >>= 1) { if (tid < off) red[tid] += red[tid + off]; __syncthreads(); }
    float mu = red[0] * (1.0f / D_);
    __syncthreads();
    float s2 = 0.f;
#pragma unroll
    for (int u = 0; u < 3; ++u) { float d = v[u] - mu; s2 += d * d; }
    red[tid] = s2; __syncthreads();
    for (int off = 128; off > 0; off >>= 1) { if (tid < off) red[tid] += red[tid + off]; __syncthreads(); }
    float rstd = rsqrtf(red[0] * (1.0f / D_) + 1e-5f);
#pragma unroll
    for (int u = 0; u < 3; ++u) {
        int d = tid + 256 * u;
        float yv = (v[u] - mu) * rstd * g[d] + b[d];
        u16 h = f2bf(yv);
        yh[d] = h;
        yl[d] = f2bf(yv - bf2f(h));
    }
}

// ---------------- attention softmax: in-place on bf16 hi/lo rows of SP_ ----------------
__global__ __launch_bounds__(64) void att_softmax_kernel(u16* __restrict__ hi, u16* __restrict__ lo,
                                                         float scale) {
    long long row = blockIdx.x;
    u16* ph = hi + row * SP_;
    u16* pl = lo + row * SP_;
    int tid = threadIdx.x;
    float v[4];
    float mx = -1e30f;
#pragma unroll
    for (int u = 0; u < 4; ++u) {
        int t = tid + 64 * u;
        v[u] = (t < S_) ? (bf2f(ph[t]) + bf2f(pl[t])) * scale : -1e30f;
        mx = fmaxf(mx, v[u]);
    }
    for (int off = 32; off > 0; off >>= 1) mx = fmaxf(mx, __shfl_xor(mx, off));
    float sum = 0.f;
#pragma unroll
    for (int u = 0; u < 4; ++u) { v[u] = expf(v[u] - mx); sum += v[u]; }
    for (int off = 32; off > 0; off >>= 1) sum += __shfl_xor(sum, off);
    float inv = 1.0f / sum;
#pragma unroll
    for (int u = 0; u < 4; ++u) {
        int t = tid + 64 * u;
        if (t < S_) {
            float r = v[u] * inv;
            u16 h = f2bf(r);
            ph[t] = h;
            pl[t] = f2bf(r - bf2f(h));
        }
    }
}

// ---------------- head softmax ----------------
__global__ __launch_bounds__(256) void head_softmax_kernel(const float* __restrict__ logits,
                                                           float* __restrict__ out) {
    int n = blockIdx.x;
    const float* p = logits + (long long)n * OUT_;
    int tid = threadIdx.x;
    float v[4];
    float mx = -1e30f;
#pragma unroll
    for (int u = 0; u < 4; ++u) {
        int idx = tid + 256 * u;
        v[u] = (idx < OUT_) ? p[idx] : -1e30f;
        mx = fmaxf(mx, v[u]);
    }
    __shared__ float red[256];
    red[tid] = mx; __syncthreads();
    for (int off = 128; off > 0; off >>= 1) { if (tid < off) red[tid] = fmaxf(red[tid], red[tid + off]); __syncthreads(); }
    mx = red[0];
    __syncthreads();
    float sum = 0.f;
#pragma unroll
    for (int u = 0; u < 4; ++u) { v[u] = expf(v[u] - mx); sum += v[u]; }
    red[tid] = sum; __syncthreads();
    for (int off = 128; off > 0; off >>= 1) { if (tid < off) red[tid] += red[tid + off]; __syncthreads(); }
    float inv = 1.0f / red[0];
#pragma unroll
    for (int u = 0; u < 4; ++u) {
        int idx = tid + 256 * u;
        if (idx < OUT_) out[(long long)n * OUT_ + idx] = v[u] * inv;
    }
}

// ---------------- host helpers ----------------
struct Off { int div; long long so, si; };
static const Off Z0 = {1, 0, 0};

static inline void launch_gemm(hipStream_t st, const float* A, const float* Bm, const float* bias,
                               float* C, int M, int N, int K, int lda, int ldb, int ldc,
                               int transB, int act, int accum, int batch,
                               Off a, Off b, Off c, Off bb) {
    dim3 grid((N + BN - 1) / BN, (M + BM - 1) / BM, batch);
    gemm_kernel<<<grid, dim3(256), 0, st>>>(A, Bm, bias, C, M, N, K, lda, ldb, ldc,
                                            transB, act, accum,
                                            a.div, a.so, a.si, b.div, b.so, b.si,
                                            c.div, c.so, c.si, bb.div, bb.so, bb.si);
}

static inline void launch_mfma(hipStream_t st,
                               const u16* Ahi, const u16* Alo, const u16* Bhi, const u16* Blo,
                               const float* bias, float* C, u16* Ohi, u16* Olo,
                               int M, int N, int K, int lda, int ldb, int ldc,
                               int mode, int accum, int remap, int batch, int ksplit,
                               Off a, Off b, Off c, Off bb) {
    dim3 grid((N + 127) / 128, (M + 127) / 128, batch);
    mfma_gemm_kernel<<<grid, dim3(256), 0, st>>>(Ahi, Alo, Bhi, Blo, bias, C, Ohi, Olo,
                                                 M, N, K, lda, ldb, ldc, mode, accum, remap, ksplit,
                                                 a.div, a.so, a.si, b.div, b.so, b.si,
                                                 c.div, c.so, c.si, bb.div, bb.so, bb.si);
}

extern "C" void kernel_launch(void* const* d_in, const int* in_sizes, int n_in,
                              void* d_out, int out_size, void* d_ws, size_t ws_size,
                              hipStream_t stream) {
    (void)in_sizes; (void)n_in; (void)out_size; (void)ws_size;
    const float* x        = (const float*)d_in[0];
    const float* w_embed  = (const float*)d_in[1];
    const float* b_embed  = (const float*)d_in[2];
    const float* cls_tok  = (const float*)d_in[3];
    const float* ln1_g    = (const float*)d_in[4];
    const float* ln1_b    = (const float*)d_in[5];
    const float* wq       = (const float*)d_in[6];
    const float* bq       = (const float*)d_in[7];
    const float* wk       = (const float*)d_in[8];
    const float* bk       = (const float*)d_in[9];
    const float* wv       = (const float*)d_in[10];
    const float* bv       = (const float*)d_in[11];
    const float* ln2_g    = (const float*)d_in[12];
    const float* ln2_b    = (const float*)d_in[13];
    const float* w1       = (const float*)d_in[14];
    const float* b1       = (const float*)d_in[15];
    const float* w2       = (const float*)d_in[16];
    const float* b2       = (const float*)d_in[17];
    const float* w_head   = (const float*)d_in[18];
    const float* b_head   = (const float*)d_in[19];
    float* out = (float*)d_out;
    char* wsb  = (char*)d_ws;

    const long long TOKSZ = (long long)B_ * S_ * D_;          // 4,841,472
    const int M_TOK = B_ * S_;                                 // 6304
    const int M_PAT = B_ * NP_ * NP_;                          // 6272
    const int NB = B_ * NH_;                                   // 384

    // ---- workspace carve (bytes, 256B aligned) ----
    auto alloc = [&](long long bytes) {
        char* p = wsb;
        wsb += (bytes + 255) & ~255LL;
        return p;
    };
    float* pos    = (float*)alloc((long long)S_ * D_ * 4);
    float* tok    = (float*)alloc(TOKSZ * 4);
    u16*   h_hi   = (u16*)alloc(TOKSZ * 2);                    // LN1/LN2 out hi
    u16*   h_lo   = (u16*)alloc(TOKSZ * 2);
    u16*   qk_hi  = (u16*)alloc((long long)NH_ * M_TOK * 128 * 2);   // [NH][B*S][128] q|k
    u16*   qk_lo  = (u16*)alloc((long long)NH_ * M_TOK * 128 * 2);
    u16*   vt_hi  = (u16*)alloc((long long)NH_ * B_ * DH_ * SP_ * 2); // [NH][B][DH][SP] v^T
    u16*   vt_lo  = (u16*)alloc((long long)NH_ * B_ * DH_ * SP_ * 2);
    u16*   w1t_hi = (u16*)alloc((long long)MLP_ * D_ * 2);     // also wet pre-loop
    u16*   w1t_lo = (u16*)alloc((long long)MLP_ * D_ * 2);
    u16*   w2t_hi = (u16*)alloc((long long)D_ * MLP_ * 2);
    u16*   w2t_lo = (u16*)alloc((long long)D_ * MLP_ * 2);
    u16*   wqk_hi = (u16*)alloc((long long)NH_ * 128 * 64 * 2);
    u16*   wqk_lo = (u16*)alloc((long long)NH_ * 128 * 64 * 2);
    u16*   wvt_hi = (u16*)alloc((long long)NH_ * 64 * 64 * 2);
    u16*   wvt_lo = (u16*)alloc((long long)NH_ * 64 * 64 * 2);
    float* bqk_f  = (float*)alloc((long long)NH_ * 128 * 4);
    // big region: max(att hi+lo 67.8MB, gelu hi+lo 77.5MB, patches hi+lo 19.3MB)
    char* bigreg  = alloc((long long)M_TOK * MLP_ * 2 * 2);
    u16*   att_hi = (u16*)bigreg;                              // [NB][S_][SP_]
    u16*   att_lo = att_hi + (long long)NB * S_ * SP_;
    u16*   g_hi   = (u16*)bigreg;                              // [M_TOK][MLP_]
    u16*   g_lo   = g_hi + (long long)M_TOK * MLP_;
    u16*   p_hi   = (u16*)bigreg;                              // [M_PAT][768] pre-loop
    u16*   p_lo   = p_hi + (long long)M_PAT * 768;
    float* logits = (float*)alloc((long long)B_ * OUT_ * 4);

    // ---- embed path ----
    posemb_kernel<<<(S_ * D_ + 255) / 256, 256, 0, stream>>>(pos);
    patchify_split_kernel<<<(M_PAT * 768 + 255) / 256, 256, 0, stream>>>(x, p_hi, p_lo);
    tconv_kernel<<<dim3(768 / 32, 768 / 32), 256, 0, stream>>>(w_embed, w1t_hi, w1t_lo, 768, 768);
    launch_mfma(stream, p_hi, p_lo, w1t_hi, w1t_lo, b_embed, tok, nullptr, nullptr,
                M_PAT, D_, 768, 768, 768, D_, 0, 0, 1, 1, 1, Z0, Z0, Z0, Z0);
    addpos_kernel<<<((int)TOKSZ + 255) / 256, 256, 0, stream>>>(tok, pos, cls_tok);
    // zero v^T (pads s in [197,224) must stay 0; data region rewritten each layer)
    {
        long long n32 = (long long)NH_ * B_ * DH_ * SP_ / 2;   // u16 count / 2
        zfill_kernel<<<(int)((n32 + 255) / 256), 256, 0, stream>>>((u32*)vt_hi, n32);
        zfill_kernel<<<(int)((n32 + 255) / 256), 256, 0, stream>>>((u32*)vt_lo, n32);
    }

    const float scale = 0.125f;
    const int QKVPREP_N = NH_ * 128 * 64 + NH_ * 64 * 64 + NH_ * 128;

    for (int l = 0; l < L_; ++l) {
        // LN1 -> bf16 hi/lo
        ln_split_kernel<<<M_TOK, 256, 0, stream>>>(tok, h_hi, h_lo, ln1_g + l * D_, ln1_b + l * D_);
        // per-layer QKV weight prep
        qkvprep_kernel<<<(QKVPREP_N + 255) / 256, 256, 0, stream>>>(
            wq + (long long)l * NH_ * DH_ * DH_, wk + (long long)l * NH_ * DH_ * DH_,
            wv + (long long)l * NH_ * DH_ * DH_,
            bq + (long long)l * NH_ * DH_, bk + (long long)l * NH_ * DH_,
            wqk_hi, wqk_lo, wvt_hi, wvt_lo, bqk_f);
        // Q|K: per-head GEMM, out bf16 hi/lo [NH][B*S][128] (cols 0-63 q, 64-127 k)
        launch_mfma(stream, h_hi, h_lo, wqk_hi, wqk_lo, bqk_f, nullptr, qk_hi, qk_lo,
                    M_TOK, 128, 64, D_, 64, 128, 2, 0, 0, NH_, 1,
                    Off{1, 64, 0}, Off{1, 128 * 64, 0},
                    Off{1, (long long)M_TOK * 128, 0}, Off{1, 128, 0});
        // V: per-head GEMM, out transposed bf16 hi/lo [NH][B][DH][SP]
        launch_mfma(stream, h_hi, h_lo, wvt_hi, wvt_lo, bv + (long long)l * NH_ * DH_,
                    nullptr, vt_hi, vt_lo,
                    M_TOK, 64, 64, D_, 64, SP_, 3, 0, 0, NH_, 1,
                    Off{1, 64, 0}, Off{1, 64 * 64, 0},
                    Off{1, (long long)B_ * DH_ * SP_, 0}, Off{1, 64, 0});
        // scores = q @ k^T per (h,n): z = h*32+n; out bf16 hi/lo [z][S_][SP_], pads zeroed
        launch_mfma(stream, qk_hi, qk_lo, qk_hi + 64, qk_lo + 64, nullptr, nullptr, att_hi, att_lo,
                    S_, S_, 64, 128, 128, SP_, 2, 0, 0, NB, 1,
                    Off{B_, (long long)M_TOK * 128, (long long)S_ * 128},
                    Off{B_, (long long)M_TOK * 128, (long long)S_ * 128},
                    Off{1, (long long)S_ * SP_, 0}, Z0);
        // softmax in place on hi/lo
        att_softmax_kernel<<<NB * S_, 64, 0, stream>>>(att_hi, att_lo, scale);
        // O = att @ v  (+residual into tok)
        launch_mfma(stream, att_hi, att_lo, vt_hi, vt_lo, nullptr, tok, nullptr, nullptr,
                    S_, DH_, SP_, SP_, SP_, D_, 0, 1, 0, NB, 1,
                    Off{1, (long long)S_ * SP_, 0},
                    Off{B_, (long long)B_ * DH_ * SP_, (long long)DH_ * SP_},
                    Off{B_, 64, (long long)S_ * D_}, Z0);
        // LN2 -> bf16 hi/lo
        ln_split_kernel<<<M_TOK, 256, 0, stream>>>(tok, h_hi, h_lo, ln2_g + l * D_, ln2_b + l * D_);
        // weights -> transposed bf16 hi/lo
        tconv_kernel<<<dim3(MLP_ / 32, D_ / 32), 256, 0, stream>>>(
            w1 + (long long)l * D_ * MLP_, w1t_hi, w1t_lo, D_, MLP_);
        tconv_kernel<<<dim3(D_ / 32, MLP_ / 32), 256, 0, stream>>>(
            w2 + (long long)l * MLP_ * D_, w2t_hi, w2t_lo, MLP_, D_);
        // MLP1: gelu(h @ w1 + b1) -> g hi/lo (bf16)
        launch_mfma(stream, h_hi, h_lo, w1t_hi, w1t_lo, b1 + (long long)l * MLP_,
                    nullptr, g_hi, g_lo, M_TOK, MLP_, D_, D_, D_, MLP_, 1, 0, 0, 1, 1,
                    Z0, Z0, Z0, Z0);
        // MLP2: tok += g @ w2 + b2  -- split-K x4: 1200 blocks, atomicAdd epilogue
        launch_mfma(stream, g_hi, g_lo, w2t_hi, w2t_lo, b2 + (long long)l * D_,
                    tok, nullptr, nullptr, M_TOK, D_, MLP_, MLP_, MLP_, D_, 0, 1, 0, 4, 4,
                    Z0, Z0, Z0, Z0);
    }

    // head (fp32, tiny)
    launch_gemm(stream, tok, w_head, b_head, logits,
                B_, OUT_, D_, S_ * D_, OUT_, OUT_, 0, 0, 0, 1, Z0, Z0, Z0, Z0);
    head_softmax_kernel<<<B_, 256, 0, stream>>>(logits, out);
}

// Round 4
// 8841.498 us; speedup vs baseline: 1.3674x; 1.3674x over previous
//
#include <hip/hip_runtime.h>
#include <math.h>

// ---------------- dims ----------------
#define B_ 32
#define C_ 3
#define HW_ 224
#define NP_ 14
#define PS_ 16
#define S_ 197        // NP*NP + 1
#define SP_ 224       // S padded to multiple of 32 (K dim of AV)
#define D_ 768
#define NH_ 12
#define DH_ 64
#define L_ 12
#define MLP_ 3072
#define OUT_ 1000

#define BM 64
#define BN 64
#define BK 16

// blocked (K-octet-major) layouts: buf[k/8][rows][8] -> fully coalesced
// global_load_lds staging (lane i reads base + i*16B, 1KB burst/instruction).
#define OID(rows, r, k) ((((long long)((k) >> 3)) * (rows) + (r)) * 8 + ((k) & 7))

#define NBS_ (B_ * NH_ * S_)          // 75648 rows of att
#define VROWS_ (NH_ * B_ * DH_)       // 24576 rows of vt

typedef unsigned short u16;
typedef unsigned int u32;
typedef __attribute__((ext_vector_type(8))) short short8_t;
typedef __attribute__((ext_vector_type(4))) float f32x4;
typedef const __attribute__((address_space(1))) u16 gq_t;
typedef __attribute__((address_space(3))) u16 lq_t;

// ---------------- bf16 helpers ----------------
__device__ __forceinline__ u16 f2bf(float x) {
    union { float f; u32 u; } a; a.f = x;
    u32 r = (a.u + 0x7fffu + ((a.u >> 16) & 1u)) >> 16;   // RNE
    return (u16)r;
}
__device__ __forceinline__ float bf2f(u16 h) {
    union { u32 u; float f; } a; a.u = ((u32)h) << 16; return a.f;
}

// ================= bf16x3 split MFMA GEMM (blocked operands) =================
// C = A @ B^T(stored blocked [K/8][rowsN][8]) with hi/lo bf16 decomposition.
// 3 MFMAs per product: hi*hi + hi*lo + lo*hi  (~2^-16 relative error).
// A is blocked [K/8][rowsM][8]; mplaneA/mplaneB = rows per k-octet plane.
// Per-z offsets: off = (z/div)*so + (z%div)*si (element offsets into blocked bufs;
// row offsets enter as row*8, plane-group offsets as nplanes*rows*8).
// ksplit>1: blockIdx.z = K chunk; epilogue atomicAdd into C; bias only chunk 0.
// mode 0: C[row*ldc+col] = acc+bias (+C_old if accum); remap row=grow+grow/196+1
// mode 1: gelu(acc+bias) -> blocked bf16 hi/lo at OID(orows, grow, col)
// mode 2: (acc+bias)     -> blocked bf16 hi/lo at OID(orows, grow, col),
//         zero-fills cols [N,ldc)
// mode 3: (acc+bias)     -> blocked bf16 hi/lo v^T: OID(orows, nn*DH_+col, ss)
__global__ __launch_bounds__(256) void mfma_gemm_kernel(
    const u16* __restrict__ Ahi, const u16* __restrict__ Alo,
    const u16* __restrict__ Bhi, const u16* __restrict__ Blo,
    const float* __restrict__ bias, float* __restrict__ C,
    u16* __restrict__ Ohi, u16* __restrict__ Olo,
    int M, int N, int K, int mplaneA, int mplaneB, int ldc, long long orows,
    int mode, int accum, int remap, int ksplit,
    int divA, long long sAo, long long sAi,
    int divB, long long sBo, long long sBi,
    int divC, long long sCo, long long sCi,
    int divBias, long long sBiaso, long long sBiasi)
{
    // chunk-major LDS: [buf][mat][k-octet][row][8 bf16] -> conflict-free b128 reads,
    // and global_load_lds lands lane L at row h*64+L (contiguous 16B/lane).
    __shared__ u16 lds[2][4][4][128][8];   // 64 KB

    int z = blockIdx.z;
    int kz = 0;
    if (ksplit > 1) { kz = z; z = 0; }
    long long aoff = (long long)(z / divA) * sAo + (long long)(z % divA) * sAi;
    long long boff = (long long)(z / divB) * sBo + (long long)(z % divB) * sBi;
    long long coff = (long long)(z / divC) * sCo + (long long)(z % divC) * sCi;
    long long biasoff = (long long)(z / divBias) * sBiaso + (long long)(z % divBias) * sBiasi;

    // ---- bijective XCD-chunked swizzle of the 2D grid (m204) ----
    int nwgx = gridDim.x;
    int nwg = nwgx * gridDim.y;
    int bid = blockIdx.y * nwgx + blockIdx.x;
    int xcd = bid & 7, lid = bid >> 3;
    int qq = nwg >> 3, rr8 = nwg & 7;
    int sw = ((xcd < rr8) ? xcd * (qq + 1) : rr8 * (qq + 1) + (xcd - rr8) * qq) + lid;
    int bx = sw % nwgx, by = sw / nwgx;

    int tid = threadIdx.x;
    int lane = tid & 63;
    int w = tid >> 6;                  // wave id 0..3
    int wm = (w >> 1) * 64, wn = (w & 1) * 64;
    int m0 = by * 128, n0 = bx * 128;
    int lm = lane & 15, qd = lane >> 4;

    const u16* src;
    int mp, base, rmax;
    if (w < 2) { src = ((w == 0) ? Ahi : Alo) + aoff; mp = mplaneA; base = m0; rmax = M - 1; }
    else       { src = ((w == 2) ? Bhi : Blo) + boff; mp = mplaneB; base = n0; rmax = N - 1; }

    int kc = K / ksplit;
    int kbeg = kz * kc;
    int nsteps = kc / 32;

    // stage: wave w loads matrix w's 128x32 tile; blocked layout -> each
    // global_load_lds is a 1KB contiguous burst (lane L at +L*16B).
    auto STAGE = [&](int buf, int k0) {
        int r0 = base + lane;
#pragma unroll
        for (int q = 0; q < 4; ++q) {
#pragma unroll
            for (int h = 0; h < 2; ++h) {
                int rr = r0 + h * 64;
                rr = rr > rmax ? rmax : rr;
                const u16* gp = src + ((long long)((k0 >> 3) + q) * mp + rr) * 8;
                u16* lp = &lds[buf][w][q][h * 64][0];
                __builtin_amdgcn_global_load_lds((gq_t*)gp, (lq_t*)lp, 16, 0, 0);
            }
        }
    };

    f32x4 acc[4][4];
#pragma unroll
    for (int i = 0; i < 4; ++i)
#pragma unroll
        for (int j = 0; j < 4; ++j)
            acc[i][j] = (f32x4){0.f, 0.f, 0.f, 0.f};

    STAGE(0, kbeg);
    __syncthreads();

    for (int t = 0; t < nsteps; ++t) {
        int cur = t & 1;
        if (t + 1 < nsteps) STAGE(cur ^ 1, kbeg + (t + 1) * 32);   // prefetch next tile

        short8_t ah[4], al[4], bh[4], bl[4];
#pragma unroll
        for (int i = 0; i < 4; ++i) {
            ah[i] = *(const short8_t*)&lds[cur][0][qd][wm + i * 16 + lm][0];
            al[i] = *(const short8_t*)&lds[cur][1][qd][wm + i * 16 + lm][0];
            bh[i] = *(const short8_t*)&lds[cur][2][qd][wn + i * 16 + lm][0];
            bl[i] = *(const short8_t*)&lds[cur][3][qd][wn + i * 16 + lm][0];
        }
#pragma unroll
        for (int i = 0; i < 4; ++i)
#pragma unroll
            for (int j = 0; j < 4; ++j) {
                acc[i][j] = __builtin_amdgcn_mfma_f32_16x16x32_bf16(ah[i], bh[j], acc[i][j], 0, 0, 0);
                acc[i][j] = __builtin_amdgcn_mfma_f32_16x16x32_bf16(ah[i], bl[j], acc[i][j], 0, 0, 0);
                acc[i][j] = __builtin_amdgcn_mfma_f32_16x16x32_bf16(al[i], bh[j], acc[i][j], 0, 0, 0);
            }
        __syncthreads();
    }

    float* Cb = C ? C + coff : nullptr;
    u16* Ohb = Ohi ? Ohi + coff : nullptr;
    u16* Olb = Olo ? Olo + coff : nullptr;
    const float* biasb = (bias && kz == 0) ? bias + biasoff : nullptr;

    // ---- epilogue: C/D layout col=lane&15, row=quad*4+reg ----
#pragma unroll
    for (int j = 0; j < 4; ++j) {
        int col = n0 + wn + j * 16 + lm;
        bool cok = col < N;
        float bv = (cok && biasb) ? biasb[col] : 0.f;
#pragma unroll
        for (int i = 0; i < 4; ++i) {
#pragma unroll
            for (int r = 0; r < 4; ++r) {
                int grow = m0 + wm + i * 16 + qd * 4 + r;
                if (grow >= M) continue;
                float v = acc[i][j][r] + bv;
                if (mode == 2) {
                    if (col >= ldc) continue;          // never cross plane range
                    if (!cok) v = 0.f;                 // zero-fill K padding
                    u16 h = f2bf(v);
                    long long idx = OID(orows, grow, col);
                    Ohb[idx] = h;
                    Olb[idx] = f2bf(v - bf2f(h));
                } else if (mode == 3) {
                    if (!cok) continue;
                    int nn = grow / S_;
                    int ss = grow - nn * S_;
                    long long idx = OID(orows, nn * DH_ + col, ss);
                    u16 h = f2bf(v);
                    Ohb[idx] = h;
                    Olb[idx] = f2bf(v - bf2f(h));
                } else if (mode == 1) {
                    if (!cok) continue;
                    v = 0.5f * v * (1.0f + erff(v * 0.70710678118654752f));
                    u16 h = f2bf(v);
                    long long idx = OID(orows, grow, col);
                    Ohb[idx] = h;
                    Olb[idx] = f2bf(v - bf2f(h));
                } else {
                    if (!cok) continue;
                    int orow = remap ? (grow + grow / 196 + 1) : grow;
                    long long idx = (long long)orow * ldc + col;
                    if (ksplit > 1) {
                        atomicAdd(&Cb[idx], v);        // accum semantics, nondet order
                    } else {
                        if (accum) v += Cb[idx];
                        Cb[idx] = v;
                    }
                }
            }
        }
    }
}

// ---------------- transpose + hi/lo split of fp32 weights (blocked out) ----------------
// in:  W [K][N] fp32 row-major;  out: Thi/Tlo blocked [K/8][N][8] bf16
__global__ __launch_bounds__(256) void tconv_kernel(const float* __restrict__ W,
                                                    u16* __restrict__ Thi, u16* __restrict__ Tlo,
                                                    int K, int N)
{
    __shared__ float t[32][33];
    int n0 = blockIdx.x * 32, k0 = blockIdx.y * 32;
    int tc = threadIdx.x & 31, tr = threadIdx.x >> 5;   // tr in 0..7
#pragma unroll
    for (int u = 0; u < 4; ++u) {
        int kk = tr + u * 8;
        t[kk][tc] = W[(long long)(k0 + kk) * N + n0 + tc];
    }
    __syncthreads();
#pragma unroll
    for (int u = 0; u < 4; ++u) {
        int nn = tr + u * 8;
        float v = t[tc][nn];
        u16 h = f2bf(v);
        long long idx = OID(N, n0 + nn, k0 + tc);
        Thi[idx] = h;
        Tlo[idx] = f2bf(v - bf2f(h));
    }
}

// ---------------- per-layer QKV weight prep (blocked out) ----------------
// wqk blocked per h: [8][128][8] (rows j=0..127: q|k, k=d);  wvt per h: [8][64][8]
__global__ void qkvprep_kernel(const float* __restrict__ wq, const float* __restrict__ wk,
                               const float* __restrict__ wv,
                               const float* __restrict__ bq, const float* __restrict__ bk,
                               u16* __restrict__ qkh, u16* __restrict__ qkl,
                               u16* __restrict__ vth, u16* __restrict__ vtl,
                               float* __restrict__ bqk)
{
    int idx = blockIdx.x * 256 + threadIdx.x;
    if (idx < NH_ * 128 * 64) {
        int d = idx & 63, j = (idx >> 6) & 127, h = idx >> 13;
        float v = (j < 64) ? wq[((h << 6) + d) * 64 + j] : wk[((h << 6) + d) * 64 + (j & 63)];
        u16 hh = f2bf(v);
        long long o = (long long)h * 8192 + ((d >> 3) * 128 + j) * 8 + (d & 7);
        qkh[o] = hh; qkl[o] = f2bf(v - bf2f(hh));
        return;
    }
    int i2 = idx - NH_ * 128 * 64;
    if (i2 < NH_ * 64 * 64) {
        int d = i2 & 63, j = (i2 >> 6) & 63, h = i2 >> 12;
        float v = wv[((h << 6) + d) * 64 + j];
        u16 hh = f2bf(v);
        long long o = (long long)h * 4096 + ((d >> 3) * 64 + j) * 8 + (d & 7);
        vth[o] = hh; vtl[o] = f2bf(v - bf2f(hh));
        return;
    }
    int i3 = i2 - NH_ * 64 * 64;
    if (i3 < NH_ * 128) {
        int j = i3 & 127, h = i3 >> 7;
        bqk[i3] = (j < 64) ? bq[(h << 6) + j] : bk[(h << 6) + (j & 63)];
    }
}

// ---------------- zero fill (u32) ----------------
__global__ void zfill_kernel(u32* __restrict__ p, long long n) {
    long long i = (long long)blockIdx.x * 256 + threadIdx.x;
    if (i < n) p[i] = 0u;
}

// ================= fp32 generic batched GEMM (head only) =================
__global__ __launch_bounds__(256) void gemm_kernel(
    const float* __restrict__ A, const float* __restrict__ Bm,
    const float* __restrict__ bias, float* __restrict__ C,
    int M, int N, int K, int lda, int ldb, int ldc,
    int transB, int act, int accum,
    int divA, long long sAo, long long sAi,
    int divB, long long sBo, long long sBi,
    int divC, long long sCo, long long sCi,
    int divBias, long long sBiaso, long long sBiasi)
{
    int z = blockIdx.z;
    const float* Ab = A + (long long)(z / divA) * sAo + (long long)(z % divA) * sAi;
    const float* Bb = Bm + (long long)(z / divB) * sBo + (long long)(z % divB) * sBi;
    float* Cb = C + (long long)(z / divC) * sCo + (long long)(z % divC) * sCi;
    const float* biasb = bias ? (bias + (long long)(z / divBias) * sBiaso + (long long)(z % divBias) * sBiasi)
                              : nullptr;

    __shared__ float As[BK][BM + 4];
    __shared__ float Bs[BK][BN + 4];

    int tid = threadIdx.x;
    int tx = tid & 15, ty = tid >> 4;
    int m0 = blockIdx.y * BM, n0 = blockIdx.x * BN;

    float acc[4][4] = {};

    for (int k0 = 0; k0 < K; k0 += BK) {
        {
            int row = tid >> 2;
            int c4 = (tid & 3) * 4;
            int gm = m0 + row;
#pragma unroll
            for (int u = 0; u < 4; ++u) {
                int gk = k0 + c4 + u;
                float v = 0.f;
                if (gm < M && gk < K) v = Ab[(long long)gm * lda + gk];
                As[c4 + u][row] = v;
            }
        }
        if (!transB) {
            int row = tid >> 4;
            int c4 = (tid & 15) * 4;
            int gk = k0 + row;
#pragma unroll
            for (int u = 0; u < 4; ++u) {
                int gn = n0 + c4 + u;
                float v = 0.f;
                if (gk < K && gn < N) v = Bb[(long long)gk * ldb + gn];
                Bs[row][c4 + u] = v;
            }
        } else {
            int row = tid >> 2;
            int c4 = (tid & 3) * 4;
            int gn = n0 + row;
#pragma unroll
            for (int u = 0; u < 4; ++u) {
                int gk = k0 + c4 + u;
                float v = 0.f;
                if (gn < N && gk < K) v = Bb[(long long)gn * ldb + gk];
                Bs[c4 + u][row] = v;
            }
        }
        __syncthreads();
#pragma unroll
        for (int kk = 0; kk < BK; ++kk) {
            float a[4], b[4];
#pragma unroll
            for (int i = 0; i < 4; ++i) a[i] = As[kk][ty * 4 + i];
#pragma unroll
            for (int j = 0; j < 4; ++j) b[j] = Bs[kk][tx * 4 + j];
#pragma unroll
            for (int i = 0; i < 4; ++i)
#pragma unroll
                for (int j = 0; j < 4; ++j)
                    acc[i][j] += a[i] * b[j];
        }
        __syncthreads();
    }

#pragma unroll
    for (int i = 0; i < 4; ++i) {
        int gm = m0 + ty * 4 + i;
        if (gm >= M) continue;
#pragma unroll
        for (int j = 0; j < 4; ++j) {
            int gn = n0 + tx * 4 + j;
            if (gn >= N) continue;
            float v = acc[i][j];
            if (biasb) v += biasb[gn];
            if (act == 1) v = 0.5f * v * (1.0f + erff(v * 0.70710678118654752f));
            long long idx = (long long)gm * ldc + gn;
            if (accum) v += Cb[idx];
            Cb[idx] = v;
        }
    }
}

// ---------------- positional embedding ----------------
__global__ void posemb_kernel(float* __restrict__ pos) {
    int idx = blockIdx.x * 256 + threadIdx.x;
    if (idx >= S_ * D_) return;
    int s = idx / D_, d = idx % D_;
    float jj = (float)(d & ~1);
    float freq = powf(10000.0f, jj / (float)D_);
    float arg = (float)s / freq;
    pos[idx] = (d & 1) ? cosf(arg) : sinf(arg);
}

// ---------------- patchify (blocked bf16 hi/lo out) ----------------
__global__ void patchify_split_kernel(const float* __restrict__ x,
                                      u16* __restrict__ phi, u16* __restrict__ plo) {
    int idx = blockIdx.x * 256 + threadIdx.x;
    if (idx >= B_ * NP_ * NP_ * 768) return;
    int k = idx % 768;
    int row = idx / 768;                  // n*196 + p
    int p = row % (NP_ * NP_);
    int n = row / (NP_ * NP_);
    int c = k >> 8;
    int rem = k & 255;
    int a = rem >> 4;
    int b = rem & 15;
    int i = p / NP_, j = p % NP_;
    float v = x[(((long long)n * C_ + c) * HW_ + (i * PS_ + a)) * HW_ + (j * PS_ + b)];
    u16 h = f2bf(v);
    long long o = OID(B_ * NP_ * NP_, row, k);
    phi[o] = h;
    plo[o] = f2bf(v - bf2f(h));
}

// ---------------- cls token + pos emb ----------------
__global__ void addpos_kernel(float* __restrict__ tok, const float* __restrict__ pos,
                              const float* __restrict__ cls) {
    int idx = blockIdx.x * 256 + threadIdx.x;
    if (idx >= B_ * S_ * D_) return;
    int r = idx % (S_ * D_);
    int s = r / D_, d = r % D_;
    if (s == 0) tok[idx] = cls[d] + pos[d];
    else tok[idx] += pos[r];
}

// ---------------- layernorm, blocked bf16 hi/lo out ----------------
__global__ __launch_bounds__(256) void ln_split_kernel(const float* __restrict__ x,
                                                       u16* __restrict__ yhi, u16* __restrict__ ylo,
                                                       const float* __restrict__ g, const float* __restrict__ b) {
    int row = blockIdx.x;
    const float* xr = x + (long long)row * D_;
    int tid = threadIdx.x;
    float v[3];
    float s = 0.f;
#pragma unroll
    for (int u = 0; u < 3; ++u) { v[u] = xr[tid + 256 * u]; s += v[u]; }
    __shared__ float red[256];
    red[tid] = s; __syncthreads();
    for (int off = 128; off > 0; off >>= 1) { if (tid < off) red[tid] += red[tid + off]; __syncthreads(); }
    float mu = red[0] * (1.0f / D_);
    __syncthreads();
    float s2 = 0.f;
#pragma unroll
    for (int u = 0; u < 3; ++u) { float d = v[u] - mu; s2 += d * d; }
    red[tid] = s2; __syncthreads();
    for (int off = 128; off > 0; off >>= 1) { if (tid < off) red[tid] += red[tid + off]; __syncthreads(); }
    float rstd = rsqrtf(red[0] * (1.0f / D_) + 1e-5f);
#pragma unroll
    for (int u = 0; u < 3; ++u) {
        int d = tid + 256 * u;
        float yv = (v[u] - mu) * rstd * g[d] + b[d];
        u16 h = f2bf(yv);
        long long o = OID(B_ * S_, row, d);
        yhi[o] = h;
        ylo[o] = f2bf(yv - bf2f(h));
    }
}

// ---------------- attention softmax: in-place on blocked bf16 hi/lo ----------------
__global__ __launch_bounds__(64) void att_softmax_kernel(u16* __restrict__ hi, u16* __restrict__ lo,
                                                         float scale) {
    long long rbase = (long long)blockIdx.x * 8;   // row enters OID as row*8
    int tid = threadIdx.x;
    float v[4];
    long long ix[4];
    float mx = -1e30f;
#pragma unroll
    for (int u = 0; u < 4; ++u) {
        int t = tid + 64 * u;
        ix[u] = (long long)(t >> 3) * (NBS_ * 8LL) + rbase + (t & 7);
        v[u] = (t < S_) ? (bf2f(hi[ix[u]]) + bf2f(lo[ix[u]])) * scale : -1e30f;
        mx = fmaxf(mx, v[u]);
    }
    for (int off = 32; off > 0; off >>= 1) mx = fmaxf(mx, __shfl_xor(mx, off));
    float sum = 0.f;
#pragma unroll
    for (int u = 0; u < 4; ++u) { v[u] = expf(v[u] - mx); sum += v[u]; }
    for (int off = 32; off > 0; off >>= 1) sum += __shfl_xor(sum, off);
    float inv = 1.0f / sum;
#pragma unroll
    for (int u = 0; u < 4; ++u) {
        int t = tid + 64 * u;
        if (t < S_) {
            float r = v[u] * inv;
            u16 h = f2bf(r);
            hi[ix[u]] = h;
            lo[ix[u]] = f2bf(r - bf2f(h));
        }
    }
}

// ---------------- head softmax ----------------
__global__ __launch_bounds__(256) void head_softmax_kernel(const float* __restrict__ logits,
                                                           float* __restrict__ out) {
    int n = blockIdx.x;
    const float* p = logits + (long long)n * OUT_;
    int tid = threadIdx.x;
    float v[4];
    float mx = -1e30f;
#pragma unroll
    for (int u = 0; u < 4; ++u) {
        int idx = tid + 256 * u;
        v[u] = (idx < OUT_) ? p[idx] : -1e30f;
        mx = fmaxf(mx, v[u]);
    }
    __shared__ float red[256];
    red[tid] = mx; __syncthreads();
    for (int off = 128; off > 0; off >>= 1) { if (tid < off) red[tid] = fmaxf(red[tid], red[tid + off]); __syncthreads(); }
    mx = red[0];
    __syncthreads();
    float sum = 0.f;
#pragma unroll
    for (int u = 0; u < 4; ++u) { v[u] = expf(v[u] - mx); sum += v[u]; }
    red[tid] = sum; __syncthreads();
    for (int off = 128; off > 0; off >>= 1) { if (tid < off) red[tid] += red[tid + off]; __syncthreads(); }
    float inv = 1.0f / red[0];
#pragma unroll
    for (int u = 0; u < 4; ++u) {
        int idx = tid + 256 * u;
        if (idx < OUT_) out[(long long)n * OUT_ + idx] = v[u] * inv;
    }
}

// ---------------- host helpers ----------------
struct Off { int div; long long so, si; };
static const Off Z0 = {1, 0, 0};

static inline void launch_gemm(hipStream_t st, const float* A, const float* Bm, const float* bias,
                               float* C, int M, int N, int K, int lda, int ldb, int ldc,
                               int transB, int act, int accum, int batch,
                               Off a, Off b, Off c, Off bb) {
    dim3 grid((N + BN - 1) / BN, (M + BM - 1) / BM, batch);
    gemm_kernel<<<grid, dim3(256), 0, st>>>(A, Bm, bias, C, M, N, K, lda, ldb, ldc,
                                            transB, act, accum,
                                            a.div, a.so, a.si, b.div, b.so, b.si,
                                            c.div, c.so, c.si, bb.div, bb.so, bb.si);
}

static inline void launch_mfma(hipStream_t st,
                               const u16* Ahi, const u16* Alo, const u16* Bhi, const u16* Blo,
                               const float* bias, float* C, u16* Ohi, u16* Olo,
                               int M, int N, int K, int mplaneA, int mplaneB, int ldc, long long orows,
                               int mode, int accum, int remap, int batch, int ksplit,
                               Off a, Off b, Off c, Off bb) {
    dim3 grid((N + 127) / 128, (M + 127) / 128, batch);
    mfma_gemm_kernel<<<grid, dim3(256), 0, st>>>(Ahi, Alo, Bhi, Blo, bias, C, Ohi, Olo,
                                                 M, N, K, mplaneA, mplaneB, ldc, orows,
                                                 mode, accum, remap, ksplit,
                                                 a.div, a.so, a.si, b.div, b.so, b.si,
                                                 c.div, c.so, c.si, bb.div, bb.so, bb.si);
}

extern "C" void kernel_launch(void* const* d_in, const int* in_sizes, int n_in,
                              void* d_out, int out_size, void* d_ws, size_t ws_size,
                              hipStream_t stream) {
    (void)in_sizes; (void)n_in; (void)out_size; (void)ws_size;
    const float* x        = (const float*)d_in[0];
    const float* w_embed  = (const float*)d_in[1];
    const float* b_embed  = (const float*)d_in[2];
    const float* cls_tok  = (const float*)d_in[3];
    const float* ln1_g    = (const float*)d_in[4];
    const float* ln1_b    = (const float*)d_in[5];
    const float* wq       = (const float*)d_in[6];
    const float* bq       = (const float*)d_in[7];
    const float* wk       = (const float*)d_in[8];
    const float* bk       = (const float*)d_in[9];
    const float* wv       = (const float*)d_in[10];
    const float* bv       = (const float*)d_in[11];
    const float* ln2_g    = (const float*)d_in[12];
    const float* ln2_b    = (const float*)d_in[13];
    const float* w1       = (const float*)d_in[14];
    const float* b1       = (const float*)d_in[15];
    const float* w2       = (const float*)d_in[16];
    const float* b2       = (const float*)d_in[17];
    const float* w_head   = (const float*)d_in[18];
    const float* b_head   = (const float*)d_in[19];
    float* out = (float*)d_out;
    char* wsb  = (char*)d_ws;

    const long long TOKSZ = (long long)B_ * S_ * D_;          // 4,841,472
    const int M_TOK = B_ * S_;                                 // 6304
    const int M_PAT = B_ * NP_ * NP_;                          // 6272
    const int NB = B_ * NH_;                                   // 384

    // ---- workspace carve (bytes, 256B aligned) ----
    auto alloc = [&](long long bytes) {
        char* p = wsb;
        wsb += (bytes + 255) & ~255LL;
        return p;
    };
    float* pos    = (float*)alloc((long long)S_ * D_ * 4);
    float* tok    = (float*)alloc(TOKSZ * 4);
    u16*   h_hi   = (u16*)alloc(TOKSZ * 2);                    // LN out, blocked [96][M_TOK][8]
    u16*   h_lo   = (u16*)alloc(TOKSZ * 2);
    u16*   qk_hi  = (u16*)alloc((long long)NH_ * M_TOK * 128 * 2);   // per h: [16][M_TOK][8]
    u16*   qk_lo  = (u16*)alloc((long long)NH_ * M_TOK * 128 * 2);
    u16*   vt_hi  = (u16*)alloc((long long)SP_ / 8 * VROWS_ * 8 * 2); // [28][VROWS][8]
    u16*   vt_lo  = (u16*)alloc((long long)SP_ / 8 * VROWS_ * 8 * 2);
    u16*   w1t_hi = (u16*)alloc((long long)MLP_ * D_ * 2);     // blocked [96][MLP][8]; wet pre-loop
    u16*   w1t_lo = (u16*)alloc((long long)MLP_ * D_ * 2);
    u16*   w2t_hi = (u16*)alloc((long long)D_ * MLP_ * 2);     // blocked [384][768][8]
    u16*   w2t_lo = (u16*)alloc((long long)D_ * MLP_ * 2);
    u16*   wqk_hi = (u16*)alloc((long long)NH_ * 128 * 64 * 2);
    u16*   wqk_lo = (u16*)alloc((long long)NH_ * 128 * 64 * 2);
    u16*   wvt_hi = (u16*)alloc((long long)NH_ * 64 * 64 * 2);
    u16*   wvt_lo = (u16*)alloc((long long)NH_ * 64 * 64 * 2);
    float* bqk_f  = (float*)alloc((long long)NH_ * 128 * 4);
    // big region: max(att hi+lo 67.8MB, gelu hi+lo 77.5MB, patches hi+lo 19.3MB)
    char* bigreg  = alloc((long long)M_TOK * MLP_ * 2 * 2);
    u16*   att_hi = (u16*)bigreg;                              // blocked [28][NBS_][8]
    u16*   att_lo = att_hi + (long long)NBS_ * SP_;
    u16*   g_hi   = (u16*)bigreg;                              // blocked [384][M_TOK][8]
    u16*   g_lo   = g_hi + (long long)M_TOK * MLP_;
    u16*   p_hi   = (u16*)bigreg;                              // blocked [96][M_PAT][8] pre-loop
    u16*   p_lo   = p_hi + (long long)M_PAT * 768;
    float* logits = (float*)alloc((long long)B_ * OUT_ * 4);

    // ---- embed path ----
    posemb_kernel<<<(S_ * D_ + 255) / 256, 256, 0, stream>>>(pos);
    patchify_split_kernel<<<(M_PAT * 768 + 255) / 256, 256, 0, stream>>>(x, p_hi, p_lo);
    tconv_kernel<<<dim3(768 / 32, 768 / 32), 256, 0, stream>>>(w_embed, w1t_hi, w1t_lo, 768, 768);
    launch_mfma(stream, p_hi, p_lo, w1t_hi, w1t_lo, b_embed, tok, nullptr, nullptr,
                M_PAT, D_, 768, M_PAT, 768, D_, 0, 0, 0, 1, 1, 1, Z0, Z0, Z0, Z0);
    addpos_kernel<<<((int)TOKSZ + 255) / 256, 256, 0, stream>>>(tok, pos, cls_tok);
    // zero v^T (pads kv in [197,224) must stay 0; live region rewritten each layer)
    {
        long long n32 = (long long)SP_ / 8 * VROWS_ * 8 / 2;   // u16 count / 2
        zfill_kernel<<<(int)((n32 + 255) / 256), 256, 0, stream>>>((u32*)vt_hi, n32);
        zfill_kernel<<<(int)((n32 + 255) / 256), 256, 0, stream>>>((u32*)vt_lo, n32);
    }

    const float scale = 0.125f;
    const int QKVPREP_N = NH_ * 128 * 64 + NH_ * 64 * 64 + NH_ * 128;

    for (int l = 0; l < L_; ++l) {
        // LN1 -> blocked bf16 hi/lo
        ln_split_kernel<<<M_TOK, 256, 0, stream>>>(tok, h_hi, h_lo, ln1_g + l * D_, ln1_b + l * D_);
        // per-layer QKV weight prep (blocked)
        qkvprep_kernel<<<(QKVPREP_N + 255) / 256, 256, 0, stream>>>(
            wq + (long long)l * NH_ * DH_ * DH_, wk + (long long)l * NH_ * DH_ * DH_,
            wv + (long long)l * NH_ * DH_ * DH_,
            bq + (long long)l * NH_ * DH_, bk + (long long)l * NH_ * DH_,
            wqk_hi, wqk_lo, wvt_hi, wvt_lo, bqk_f);
        // Q|K: per-head GEMM; A = h planes [8z..8z+8); out blocked per h
        launch_mfma(stream, h_hi, h_lo, wqk_hi, wqk_lo, bqk_f, nullptr, qk_hi, qk_lo,
                    M_TOK, 128, 64, M_TOK, 128, 128, M_TOK, 2, 0, 0, NH_, 1,
                    Off{1, (long long)M_TOK * 64, 0}, Off{1, 8192, 0},
                    Off{1, (long long)M_TOK * 128, 0}, Off{1, 128, 0});
        // V: per-head GEMM, out blocked v^T [28][VROWS][8]
        launch_mfma(stream, h_hi, h_lo, wvt_hi, wvt_lo, bv + (long long)l * NH_ * DH_,
                    nullptr, vt_hi, vt_lo,
                    M_TOK, 64, 64, M_TOK, 64, SP_, VROWS_, 3, 0, 0, NH_, 1,
                    Off{1, (long long)M_TOK * 64, 0}, Off{1, 4096, 0},
                    Off{1, (long long)B_ * DH_ * 8, 0}, Off{1, 64, 0});
        // scores = q @ k^T per (h,n): A = q planes, B = k planes (plane 8 base);
        // out blocked att, cols [197,224) zero-filled
        launch_mfma(stream, qk_hi, qk_lo, qk_hi + (long long)M_TOK * 64, qk_lo + (long long)M_TOK * 64,
                    nullptr, nullptr, att_hi, att_lo,
                    S_, S_, 64, M_TOK, M_TOK, SP_, NBS_, 2, 0, 0, NB, 1,
                    Off{B_, (long long)M_TOK * 128, (long long)S_ * 8},
                    Off{B_, (long long)M_TOK * 128, (long long)S_ * 8},
                    Off{1, (long long)S_ * 8, 0}, Z0);
        // softmax in place on blocked hi/lo
        att_softmax_kernel<<<NB * S_, 64, 0, stream>>>(att_hi, att_lo, scale);
        // O = att @ v  (+residual into tok, fp32 row-major)
        launch_mfma(stream, att_hi, att_lo, vt_hi, vt_lo, nullptr, tok, nullptr, nullptr,
                    S_, DH_, SP_, NBS_, VROWS_, D_, 0, 0, 1, 0, NB, 1,
                    Off{1, (long long)S_ * 8, 0},
                    Off{B_, (long long)B_ * DH_ * 8, (long long)DH_ * 8},
                    Off{B_, 64, (long long)S_ * D_}, Z0);
        // LN2 -> blocked bf16 hi/lo
        ln_split_kernel<<<M_TOK, 256, 0, stream>>>(tok, h_hi, h_lo, ln2_g + l * D_, ln2_b + l * D_);
        // weights -> blocked transposed bf16 hi/lo
        tconv_kernel<<<dim3(MLP_ / 32, D_ / 32), 256, 0, stream>>>(
            w1 + (long long)l * D_ * MLP_, w1t_hi, w1t_lo, D_, MLP_);
        tconv_kernel<<<dim3(D_ / 32, MLP_ / 32), 256, 0, stream>>>(
            w2 + (long long)l * MLP_ * D_, w2t_hi, w2t_lo, MLP_, D_);
        // MLP1: gelu(h @ w1 + b1) -> g blocked bf16 hi/lo
        launch_mfma(stream, h_hi, h_lo, w1t_hi, w1t_lo, b1 + (long long)l * MLP_,
                    nullptr, g_hi, g_lo, M_TOK, MLP_, D_, M_TOK, MLP_, MLP_, M_TOK, 1, 0, 0, 1, 1,
                    Z0, Z0, Z0, Z0);
        // MLP2: tok += g @ w2 + b2  -- split-K x4: 1200 blocks, atomicAdd epilogue
        launch_mfma(stream, g_hi, g_lo, w2t_hi, w2t_lo, b2 + (long long)l * D_,
                    tok, nullptr, nullptr, M_TOK, D_, MLP_, M_TOK, D_, D_, 0, 0, 1, 0, 4, 4,
                    Z0, Z0, Z0, Z0);
    }

    // head (fp32, tiny)
    launch_gemm(stream, tok, w_head, b_head, logits,
                B_, OUT_, D_, S_ * D_, OUT_, OUT_, 0, 0, 0, 1, Z0, Z0, Z0, Z0);
    head_softmax_kernel<<<B_, 256, 0, stream>>>(logits, out);
}

// Round 5
// 5324.909 us; speedup vs baseline: 2.2705x; 1.6604x over previous
//
#include <hip/hip_runtime.h>
#include <math.h>

// ---------------- dims ----------------
#define B_ 32
#define C_ 3
#define HW_ 224
#define NP_ 14
#define PS_ 16
#define S_ 197        // NP*NP + 1
#define SP_ 224       // S padded to multiple of 32 (K dim of AV)
#define D_ 768
#define NH_ 12
#define DH_ 64
#define L_ 12
#define MLP_ 3072
#define OUT_ 1000

#define BM 64
#define BN 64
#define BK 16

// blocked (K-octet-major) layouts: buf[k/8][rows][8] -> fully coalesced
// global_load_lds staging (lane i reads base + i*16B, 1KB burst/instruction).
#define OID(rows, r, k) ((((long long)((k) >> 3)) * (rows) + (r)) * 8 + ((k) & 7))

#define NBS_ (B_ * NH_ * S_)          // 75648 rows of att
#define VROWS_ (NH_ * B_ * DH_)       // 24576 rows of vt

typedef unsigned short u16;
typedef unsigned int u32;
typedef __attribute__((ext_vector_type(8))) _Float16 half8_t;
typedef __attribute__((ext_vector_type(4))) float f32x4;
typedef const __attribute__((address_space(1))) u16 gq_t;
typedef __attribute__((address_space(3))) u16 lq_t;

// ---------------- fp16 helpers ----------------
__device__ __forceinline__ u16 f2h(float x) {
    union { _Float16 h; u16 u; } c; c.h = (_Float16)x; return c.u;
}
__device__ __forceinline__ float h2f(u16 u) {
    union { _Float16 h; u16 u; } c; c.u = u; return (float)c.h;
}

// ================= fp16 MFMA GEMM (blocked operands, 2-phase pipelined) =================
// C = A @ B^T(stored blocked [K/8][rowsN][8]), fp16 inputs, fp32 accumulate.
// A is blocked [K/8][rowsM][8]; mplaneA/mplaneB = rows per k-octet plane.
// Per-z offsets: off = (z/div)*so + (z%div)*si (element offsets into blocked bufs).
// ksplit>1: blockIdx.z = K chunk; epilogue atomicAdd into C; bias only chunk 0.
// mode 0: C[row*ldc+col] = acc+bias (+C_old if accum); remap row=grow+grow/196+1
// mode 1: gelu(acc+bias) -> fp16 at OID(orows, grow, col)
// mode 2: (acc+bias)     -> fp16 at OID(orows, grow, col); zero-fills cols [N,ldc)
// mode 3: (acc+bias)     -> fp16 v^T: OID(orows, nn*DH_+col, ss)
__global__ __launch_bounds__(256) void mfma_gemm_kernel(
    const u16* __restrict__ Aq, const u16* __restrict__ Bq,
    const float* __restrict__ bias, float* __restrict__ C,
    u16* __restrict__ Oq,
    int M, int N, int K, int mplaneA, int mplaneB, int ldc, long long orows,
    int mode, int accum, int remap, int ksplit,
    int divA, long long sAo, long long sAi,
    int divB, long long sBo, long long sBi,
    int divC, long long sCo, long long sCi,
    int divBias, long long sBiaso, long long sBiasi)
{
    // chunk-major LDS: [buf][mat][k-octet][row][8 fp16] -> conflict-free b128 reads.
    __shared__ u16 lds[2][2][4][128][8];   // 32 KB double-buffered

    int z = blockIdx.z;
    int kz = 0;
    if (ksplit > 1) { kz = z; z = 0; }
    long long aoff = (long long)(z / divA) * sAo + (long long)(z % divA) * sAi;
    long long boff = (long long)(z / divB) * sBo + (long long)(z % divB) * sBi;
    long long coff = (long long)(z / divC) * sCo + (long long)(z % divC) * sCi;
    long long biasoff = (long long)(z / divBias) * sBiaso + (long long)(z % divBias) * sBiasi;

    // ---- bijective XCD-chunked swizzle of the 2D grid (m204) ----
    int nwgx = gridDim.x;
    int nwg = nwgx * gridDim.y;
    int bid = blockIdx.y * nwgx + blockIdx.x;
    int xcd = bid & 7, lid = bid >> 3;
    int qq = nwg >> 3, rr8 = nwg & 7;
    int sw = ((xcd < rr8) ? xcd * (qq + 1) : rr8 * (qq + 1) + (xcd - rr8) * qq) + lid;
    int bx = sw % nwgx, by = sw / nwgx;

    int tid = threadIdx.x;
    int lane = tid & 63;
    int w = tid >> 6;                  // wave id 0..3
    int wm = (w >> 1) * 64, wn = (w & 1) * 64;
    int m0 = by * 128, n0 = bx * 128;
    int lm = lane & 15, qd = lane >> 4;

    // staging role: wave pair (w>>1) -> matrix, (w&1) -> row half
    int smat = w >> 1, shh = w & 1;
    const u16* src = smat ? (Bq + boff) : (Aq + aoff);
    int mp = smat ? mplaneB : mplaneA;
    int sbase = smat ? n0 : m0;
    int srmax = smat ? (N - 1) : (M - 1);
    int sr = sbase + shh * 64 + lane;
    if (sr > srmax) sr = srmax;

    int kc = K / ksplit;
    int kbeg = kz * kc;
    int nsteps = kc / 32;

    // stage one 128x32 tile pair; each wave issues 4 x 1KB coalesced bursts
    auto STAGE = [&](int buf, int k0) {
#pragma unroll
        for (int q = 0; q < 4; ++q) {
            const u16* gp = src + ((long long)((k0 >> 3) + q) * mp + sr) * 8;
            u16* lp = &lds[buf][smat][q][shh * 64][0];
            __builtin_amdgcn_global_load_lds((gq_t*)gp, (lq_t*)lp, 16, 0, 0);
        }
    };

    f32x4 acc[4][4];
#pragma unroll
    for (int i = 0; i < 4; ++i)
#pragma unroll
        for (int j = 0; j < 4; ++j)
            acc[i][j] = (f32x4){0.f, 0.f, 0.f, 0.f};

    STAGE(0, kbeg);
    __syncthreads();

    for (int t = 0; t < nsteps; ++t) {
        int cur = t & 1;
        if (t + 1 < nsteps) STAGE(cur ^ 1, kbeg + (t + 1) * 32);   // prefetch next tile

        half8_t a[4], b[4];
#pragma unroll
        for (int i = 0; i < 4; ++i) {
            a[i] = *(const half8_t*)&lds[cur][0][qd][wm + i * 16 + lm][0];
            b[i] = *(const half8_t*)&lds[cur][1][qd][wn + i * 16 + lm][0];
        }
#pragma unroll
        for (int i = 0; i < 4; ++i)
#pragma unroll
            for (int j = 0; j < 4; ++j)
                acc[i][j] = __builtin_amdgcn_mfma_f32_16x16x32_f16(a[i], b[j], acc[i][j], 0, 0, 0);
        // one barrier per K-step: its vmcnt(0) drain waits on the prefetch issued
        // above, which had the whole ds_read+MFMA phase as head start.
        __syncthreads();
    }

    float* Cb = C ? C + coff : nullptr;
    u16* Ob = Oq ? Oq + coff : nullptr;
    const float* biasb = (bias && kz == 0) ? bias + biasoff : nullptr;

    // ---- epilogue: C/D layout col=lane&15, row=quad*4+reg ----
#pragma unroll
    for (int j = 0; j < 4; ++j) {
        int col = n0 + wn + j * 16 + lm;
        bool cok = col < N;
        float bv = (cok && biasb) ? biasb[col] : 0.f;
#pragma unroll
        for (int i = 0; i < 4; ++i) {
#pragma unroll
            for (int r = 0; r < 4; ++r) {
                int grow = m0 + wm + i * 16 + qd * 4 + r;
                if (grow >= M) continue;
                float v = acc[i][j][r] + bv;
                if (mode == 2) {
                    if (col >= ldc) continue;          // never cross plane range
                    if (!cok) v = 0.f;                 // zero-fill K padding
                    Ob[OID(orows, grow, col)] = f2h(v);
                } else if (mode == 3) {
                    if (!cok) continue;
                    int nn = grow / S_;
                    int ss = grow - nn * S_;
                    Ob[OID(orows, nn * DH_ + col, ss)] = f2h(v);
                } else if (mode == 1) {
                    if (!cok) continue;
                    v = 0.5f * v * (1.0f + erff(v * 0.70710678118654752f));
                    Ob[OID(orows, grow, col)] = f2h(v);
                } else {
                    if (!cok) continue;
                    int orow = remap ? (grow + grow / 196 + 1) : grow;
                    long long idx = (long long)orow * ldc + col;
                    if (ksplit > 1) {
                        atomicAdd(&Cb[idx], v);        // accum semantics, nondet order
                    } else {
                        if (accum) v += Cb[idx];
                        Cb[idx] = v;
                    }
                }
            }
        }
    }
}

// ---------------- transpose + fp16 convert of fp32 weights (blocked out) ----------------
// in:  W [K][N] fp32 row-major;  out: T blocked [K/8][N][8] fp16
__global__ __launch_bounds__(256) void tconv_kernel(const float* __restrict__ W,
                                                    u16* __restrict__ T,
                                                    int K, int N)
{
    __shared__ float t[32][33];
    int n0 = blockIdx.x * 32, k0 = blockIdx.y * 32;
    int tc = threadIdx.x & 31, tr = threadIdx.x >> 5;   // tr in 0..7
#pragma unroll
    for (int u = 0; u < 4; ++u) {
        int kk = tr + u * 8;
        t[kk][tc] = W[(long long)(k0 + kk) * N + n0 + tc];
    }
    __syncthreads();
#pragma unroll
    for (int u = 0; u < 4; ++u) {
        int nn = tr + u * 8;
        T[OID(N, n0 + nn, k0 + tc)] = f2h(t[tc][nn]);
    }
}

// ---------------- per-layer QKV weight prep (blocked fp16 out) ----------------
// wqk blocked per h: [8][128][8] (rows j=0..127: q|k, k=d);  wvt per h: [8][64][8]
__global__ void qkvprep_kernel(const float* __restrict__ wq, const float* __restrict__ wk,
                               const float* __restrict__ wv,
                               const float* __restrict__ bq, const float* __restrict__ bk,
                               u16* __restrict__ qkh,
                               u16* __restrict__ vth,
                               float* __restrict__ bqk)
{
    int idx = blockIdx.x * 256 + threadIdx.x;
    if (idx < NH_ * 128 * 64) {
        int d = idx & 63, j = (idx >> 6) & 127, h = idx >> 13;
        float v = (j < 64) ? wq[((h << 6) + d) * 64 + j] : wk[((h << 6) + d) * 64 + (j & 63)];
        qkh[(long long)h * 8192 + ((d >> 3) * 128 + j) * 8 + (d & 7)] = f2h(v);
        return;
    }
    int i2 = idx - NH_ * 128 * 64;
    if (i2 < NH_ * 64 * 64) {
        int d = i2 & 63, j = (i2 >> 6) & 63, h = i2 >> 12;
        vth[(long long)h * 4096 + ((d >> 3) * 64 + j) * 8 + (d & 7)] = f2h(wv[((h << 6) + d) * 64 + j]);
        return;
    }
    int i3 = i2 - NH_ * 64 * 64;
    if (i3 < NH_ * 128) {
        int j = i3 & 127, h = i3 >> 7;
        bqk[i3] = (j < 64) ? bq[(h << 6) + j] : bk[(h << 6) + (j & 63)];
    }
}

// ---------------- zero fill (u32) ----------------
__global__ void zfill_kernel(u32* __restrict__ p, long long n) {
    long long i = (long long)blockIdx.x * 256 + threadIdx.x;
    if (i < n) p[i] = 0u;
}

// ================= fp32 generic batched GEMM (head only) =================
__global__ __launch_bounds__(256) void gemm_kernel(
    const float* __restrict__ A, const float* __restrict__ Bm,
    const float* __restrict__ bias, float* __restrict__ C,
    int M, int N, int K, int lda, int ldb, int ldc,
    int transB, int act, int accum,
    int divA, long long sAo, long long sAi,
    int divB, long long sBo, long long sBi,
    int divC, long long sCo, long long sCi,
    int divBias, long long sBiaso, long long sBiasi)
{
    int z = blockIdx.z;
    const float* Ab = A + (long long)(z / divA) * sAo + (long long)(z % divA) * sAi;
    const float* Bb = Bm + (long long)(z / divB) * sBo + (long long)(z % divB) * sBi;
    float* Cb = C + (long long)(z / divC) * sCo + (long long)(z % divC) * sCi;
    const float* biasb = bias ? (bias + (long long)(z / divBias) * sBiaso + (long long)(z % divBias) * sBiasi)
                              : nullptr;

    __shared__ float As[BK][BM + 4];
    __shared__ float Bs[BK][BN + 4];

    int tid = threadIdx.x;
    int tx = tid & 15, ty = tid >> 4;
    int m0 = blockIdx.y * BM, n0 = blockIdx.x * BN;

    float acc[4][4] = {};

    for (int k0 = 0; k0 < K; k0 += BK) {
        {
            int row = tid >> 2;
            int c4 = (tid & 3) * 4;
            int gm = m0 + row;
#pragma unroll
            for (int u = 0; u < 4; ++u) {
                int gk = k0 + c4 + u;
                float v = 0.f;
                if (gm < M && gk < K) v = Ab[(long long)gm * lda + gk];
                As[c4 + u][row] = v;
            }
        }
        if (!transB) {
            int row = tid >> 4;
            int c4 = (tid & 15) * 4;
            int gk = k0 + row;
#pragma unroll
            for (int u = 0; u < 4; ++u) {
                int gn = n0 + c4 + u;
                float v = 0.f;
                if (gk < K && gn < N) v = Bb[(long long)gk * ldb + gn];
                Bs[row][c4 + u] = v;
            }
        } else {
            int row = tid >> 2;
            int c4 = (tid & 3) * 4;
            int gn = n0 + row;
#pragma unroll
            for (int u = 0; u < 4; ++u) {
                int gk = k0 + c4 + u;
                float v = 0.f;
                if (gn < N && gk < K) v = Bb[(long long)gn * ldb + gk];
                Bs[c4 + u][row] = v;
            }
        }
        __syncthreads();
#pragma unroll
        for (int kk = 0; kk < BK; ++kk) {
            float a[4], b[4];
#pragma unroll
            for (int i = 0; i < 4; ++i) a[i] = As[kk][ty * 4 + i];
#pragma unroll
            for (int j = 0; j < 4; ++j) b[j] = Bs[kk][tx * 4 + j];
#pragma unroll
            for (int i = 0; i < 4; ++i)
#pragma unroll
                for (int j = 0; j < 4; ++j)
                    acc[i][j] += a[i] * b[j];
        }
        __syncthreads();
    }

#pragma unroll
    for (int i = 0; i < 4; ++i) {
        int gm = m0 + ty * 4 + i;
        if (gm >= M) continue;
#pragma unroll
        for (int j = 0; j < 4; ++j) {
            int gn = n0 + tx * 4 + j;
            if (gn >= N) continue;
            float v = acc[i][j];
            if (biasb) v += biasb[gn];
            if (act == 1) v = 0.5f * v * (1.0f + erff(v * 0.70710678118654752f));
            long long idx = (long long)gm * ldc + gn;
            if (accum) v += Cb[idx];
            Cb[idx] = v;
        }
    }
}

// ---------------- positional embedding ----------------
__global__ void posemb_kernel(float* __restrict__ pos) {
    int idx = blockIdx.x * 256 + threadIdx.x;
    if (idx >= S_ * D_) return;
    int s = idx / D_, d = idx % D_;
    float jj = (float)(d & ~1);
    float freq = powf(10000.0f, jj / (float)D_);
    float arg = (float)s / freq;
    pos[idx] = (d & 1) ? cosf(arg) : sinf(arg);
}

// ---------------- patchify (blocked fp16 out) ----------------
__global__ void patchify_split_kernel(const float* __restrict__ x,
                                      u16* __restrict__ phi) {
    int idx = blockIdx.x * 256 + threadIdx.x;
    if (idx >= B_ * NP_ * NP_ * 768) return;
    int k = idx % 768;
    int row = idx / 768;                  // n*196 + p
    int p = row % (NP_ * NP_);
    int n = row / (NP_ * NP_);
    int c = k >> 8;
    int rem = k & 255;
    int a = rem >> 4;
    int b = rem & 15;
    int i = p / NP_, j = p % NP_;
    float v = x[(((long long)n * C_ + c) * HW_ + (i * PS_ + a)) * HW_ + (j * PS_ + b)];
    phi[OID(B_ * NP_ * NP_, row, k)] = f2h(v);
}

// ---------------- cls token + pos emb ----------------
__global__ void addpos_kernel(float* __restrict__ tok, const float* __restrict__ pos,
                              const float* __restrict__ cls) {
    int idx = blockIdx.x * 256 + threadIdx.x;
    if (idx >= B_ * S_ * D_) return;
    int r = idx % (S_ * D_);
    int s = r / D_, d = r % D_;
    if (s == 0) tok[idx] = cls[d] + pos[d];
    else tok[idx] += pos[r];
}

// ---------------- layernorm, blocked fp16 out ----------------
__global__ __launch_bounds__(256) void ln_split_kernel(const float* __restrict__ x,
                                                       u16* __restrict__ yh,
                                                       const float* __restrict__ g, const float* __restrict__ b) {
    int row = blockIdx.x;
    const float* xr = x + (long long)row * D_;
    int tid = threadIdx.x;
    float v[3];
    float s = 0.f;
#pragma unroll
    for (int u = 0; u < 3; ++u) { v[u] = xr[tid + 256 * u]; s += v[u]; }
    __shared__ float red[256];
    red[tid] = s; __syncthreads();
    for (int off = 128; off > 0; off >>= 1) { if (tid < off) red[tid] += red[tid + off]; __syncthreads(); }
    float mu = red[0] * (1.0f / D_);
    __syncthreads();
    float s2 = 0.f;
#pragma unroll
    for (int u = 0; u < 3; ++u) { float d = v[u] - mu; s2 += d * d; }
    red[tid] = s2; __syncthreads();
    for (int off = 128; off > 0; off >>= 1) { if (tid < off) red[tid] += red[tid + off]; __syncthreads(); }
    float rstd = rsqrtf(red[0] * (1.0f / D_) + 1e-5f);
#pragma unroll
    for (int u = 0; u < 3; ++u) {
        int d = tid + 256 * u;
        float yv = (v[u] - mu) * rstd * g[d] + b[d];
        yh[OID(B_ * S_, row, d)] = f2h(yv);
    }
}

// ---------------- attention softmax: in-place on blocked fp16 ----------------
__global__ __launch_bounds__(64) void att_softmax_kernel(u16* __restrict__ att, float scale) {
    long long rbase = (long long)blockIdx.x * 8;   // row enters OID as row*8
    int tid = threadIdx.x;
    float v[4];
    long long ix[4];
    float mx = -1e30f;
#pragma unroll
    for (int u = 0; u < 4; ++u) {
        int t = tid + 64 * u;
        ix[u] = (long long)(t >> 3) * (NBS_ * 8LL) + rbase + (t & 7);
        v[u] = (t < S_) ? h2f(att[ix[u]]) * scale : -1e30f;
        mx = fmaxf(mx, v[u]);
    }
    for (int off = 32; off > 0; off >>= 1) mx = fmaxf(mx, __shfl_xor(mx, off));
    float sum = 0.f;
#pragma unroll
    for (int u = 0; u < 4; ++u) { v[u] = expf(v[u] - mx); sum += v[u]; }
    for (int off = 32; off > 0; off >>= 1) sum += __shfl_xor(sum, off);
    float inv = 1.0f / sum;
#pragma unroll
    for (int u = 0; u < 4; ++u) {
        int t = tid + 64 * u;
        if (t < S_) att[ix[u]] = f2h(v[u] * inv);
    }
}

// ---------------- head softmax ----------------
__global__ __launch_bounds__(256) void head_softmax_kernel(const float* __restrict__ logits,
                                                           float* __restrict__ out) {
    int n = blockIdx.x;
    const float* p = logits + (long long)n * OUT_;
    int tid = threadIdx.x;
    float v[4];
    float mx = -1e30f;
#pragma unroll
    for (int u = 0; u < 4; ++u) {
        int idx = tid + 256 * u;
        v[u] = (idx < OUT_) ? p[idx] : -1e30f;
        mx = fmaxf(mx, v[u]);
    }
    __shared__ float red[256];
    red[tid] = mx; __syncthreads();
    for (int off = 128; off > 0; off >>= 1) { if (tid < off) red[tid] = fmaxf(red[tid], red[tid + off]); __syncthreads(); }
    mx = red[0];
    __syncthreads();
    float sum = 0.f;
#pragma unroll
    for (int u = 0; u < 4; ++u) { v[u] = expf(v[u] - mx); sum += v[u]; }
    red[tid] = sum; __syncthreads();
    for (int off = 128; off > 0; off >>= 1) { if (tid < off) red[tid] += red[tid + off]; __syncthreads(); }
    float inv = 1.0f / red[0];
#pragma unroll
    for (int u = 0; u < 4; ++u) {
        int idx = tid + 256 * u;
        if (idx < OUT_) out[(long long)n * OUT_ + idx] = v[u] * inv;
    }
}

// ---------------- host helpers ----------------
struct Off { int div; long long so, si; };
static const Off Z0 = {1, 0, 0};

static inline void launch_gemm(hipStream_t st, const float* A, const float* Bm, const float* bias,
                               float* C, int M, int N, int K, int lda, int ldb, int ldc,
                               int transB, int act, int accum, int batch,
                               Off a, Off b, Off c, Off bb) {
    dim3 grid((N + BN - 1) / BN, (M + BM - 1) / BM, batch);
    gemm_kernel<<<grid, dim3(256), 0, st>>>(A, Bm, bias, C, M, N, K, lda, ldb, ldc,
                                            transB, act, accum,
                                            a.div, a.so, a.si, b.div, b.so, b.si,
                                            c.div, c.so, c.si, bb.div, bb.so, bb.si);
}

static inline void launch_mfma(hipStream_t st,
                               const u16* Aq, const u16* Bq,
                               const float* bias, float* C, u16* Oq,
                               int M, int N, int K, int mplaneA, int mplaneB, int ldc, long long orows,
                               int mode, int accum, int remap, int batch, int ksplit,
                               Off a, Off b, Off c, Off bb) {
    dim3 grid((N + 127) / 128, (M + 127) / 128, batch);
    mfma_gemm_kernel<<<grid, dim3(256), 0, st>>>(Aq, Bq, bias, C, Oq,
                                                 M, N, K, mplaneA, mplaneB, ldc, orows,
                                                 mode, accum, remap, ksplit,
                                                 a.div, a.so, a.si, b.div, b.so, b.si,
                                                 c.div, c.so, c.si, bb.div, bb.so, bb.si);
}

extern "C" void kernel_launch(void* const* d_in, const int* in_sizes, int n_in,
                              void* d_out, int out_size, void* d_ws, size_t ws_size,
                              hipStream_t stream) {
    (void)in_sizes; (void)n_in; (void)out_size; (void)ws_size;
    const float* x        = (const float*)d_in[0];
    const float* w_embed  = (const float*)d_in[1];
    const float* b_embed  = (const float*)d_in[2];
    const float* cls_tok  = (const float*)d_in[3];
    const float* ln1_g    = (const float*)d_in[4];
    const float* ln1_b    = (const float*)d_in[5];
    const float* wq       = (const float*)d_in[6];
    const float* bq       = (const float*)d_in[7];
    const float* wk       = (const float*)d_in[8];
    const float* bk       = (const float*)d_in[9];
    const float* wv       = (const float*)d_in[10];
    const float* bv       = (const float*)d_in[11];
    const float* ln2_g    = (const float*)d_in[12];
    const float* ln2_b    = (const float*)d_in[13];
    const float* w1       = (const float*)d_in[14];
    const float* b1       = (const float*)d_in[15];
    const float* w2       = (const float*)d_in[16];
    const float* b2       = (const float*)d_in[17];
    const float* w_head   = (const float*)d_in[18];
    const float* b_head   = (const float*)d_in[19];
    float* out = (float*)d_out;
    char* wsb  = (char*)d_ws;

    const long long TOKSZ = (long long)B_ * S_ * D_;          // 4,841,472
    const int M_TOK = B_ * S_;                                 // 6304
    const int M_PAT = B_ * NP_ * NP_;                          // 6272
    const int NB = B_ * NH_;                                   // 384

    // ---- workspace carve (bytes, 256B aligned) ----
    auto alloc = [&](long long bytes) {
        char* p = wsb;
        wsb += (bytes + 255) & ~255LL;
        return p;
    };
    float* pos    = (float*)alloc((long long)S_ * D_ * 4);
    float* tok    = (float*)alloc(TOKSZ * 4);
    u16*   h_h    = (u16*)alloc(TOKSZ * 2);                    // LN out, blocked [96][M_TOK][8]
    u16*   qk_h   = (u16*)alloc((long long)NH_ * M_TOK * 128 * 2);   // per h: [16][M_TOK][8]
    u16*   vt_h   = (u16*)alloc((long long)SP_ * VROWS_ * 2);  // [28][VROWS][8]
    u16*   w1t    = (u16*)alloc((long long)MLP_ * D_ * 2);     // blocked [96][MLP][8]; wet pre-loop
    u16*   w2t    = (u16*)alloc((long long)D_ * MLP_ * 2);     // blocked [384][768][8]
    u16*   wqk    = (u16*)alloc((long long)NH_ * 128 * 64 * 2);
    u16*   wvt    = (u16*)alloc((long long)NH_ * 64 * 64 * 2);
    float* bqk_f  = (float*)alloc((long long)NH_ * 128 * 4);
    // big region: max(att 33.9MB, gelu 38.7MB, patches 9.6MB)
    char* bigreg  = alloc((long long)M_TOK * MLP_ * 2);
    u16*   att_h  = (u16*)bigreg;                              // blocked [28][NBS_][8]
    u16*   g_h    = (u16*)bigreg;                              // blocked [384][M_TOK][8]
    u16*   p_h    = (u16*)bigreg;                              // blocked [96][M_PAT][8] pre-loop
    float* logits = (float*)alloc((long long)B_ * OUT_ * 4);

    // ---- embed path ----
    posemb_kernel<<<(S_ * D_ + 255) / 256, 256, 0, stream>>>(pos);
    patchify_split_kernel<<<(M_PAT * 768 + 255) / 256, 256, 0, stream>>>(x, p_h);
    tconv_kernel<<<dim3(768 / 32, 768 / 32), 256, 0, stream>>>(w_embed, w1t, 768, 768);
    launch_mfma(stream, p_h, w1t, b_embed, tok, nullptr,
                M_PAT, D_, 768, M_PAT, 768, D_, 0, 0, 0, 1, 1, 1, Z0, Z0, Z0, Z0);
    addpos_kernel<<<((int)TOKSZ + 255) / 256, 256, 0, stream>>>(tok, pos, cls_tok);
    // zero v^T (pads kv in [197,224) must stay 0; live region rewritten each layer)
    {
        long long n32 = (long long)SP_ * VROWS_ / 2;           // u16 count / 2
        zfill_kernel<<<(int)((n32 + 255) / 256), 256, 0, stream>>>((u32*)vt_h, n32);
    }

    const float scale = 0.125f;
    const int QKVPREP_N = NH_ * 128 * 64 + NH_ * 64 * 64 + NH_ * 128;

    for (int l = 0; l < L_; ++l) {
        // LN1 -> blocked fp16
        ln_split_kernel<<<M_TOK, 256, 0, stream>>>(tok, h_h, ln1_g + l * D_, ln1_b + l * D_);
        // per-layer QKV weight prep (blocked fp16)
        qkvprep_kernel<<<(QKVPREP_N + 255) / 256, 256, 0, stream>>>(
            wq + (long long)l * NH_ * DH_ * DH_, wk + (long long)l * NH_ * DH_ * DH_,
            wv + (long long)l * NH_ * DH_ * DH_,
            bq + (long long)l * NH_ * DH_, bk + (long long)l * NH_ * DH_,
            wqk, wvt, bqk_f);
        // Q|K: per-head GEMM; A = h planes [8z..8z+8); out blocked per h
        launch_mfma(stream, h_h, wqk, bqk_f, nullptr, qk_h,
                    M_TOK, 128, 64, M_TOK, 128, 128, M_TOK, 2, 0, 0, NH_, 1,
                    Off{1, (long long)M_TOK * 64, 0}, Off{1, 8192, 0},
                    Off{1, (long long)M_TOK * 128, 0}, Off{1, 128, 0});
        // V: per-head GEMM, out blocked v^T [28][VROWS][8]
        launch_mfma(stream, h_h, wvt, bv + (long long)l * NH_ * DH_, nullptr, vt_h,
                    M_TOK, 64, 64, M_TOK, 64, SP_, VROWS_, 3, 0, 0, NH_, 1,
                    Off{1, (long long)M_TOK * 64, 0}, Off{1, 4096, 0},
                    Off{1, (long long)B_ * DH_ * 8, 0}, Off{1, 64, 0});
        // scores = q @ k^T per (h,n): A = q planes, B = k planes (plane 8 base);
        // out blocked att, cols [197,224) zero-filled
        launch_mfma(stream, qk_h, qk_h + (long long)M_TOK * 64, nullptr, nullptr, att_h,
                    S_, S_, 64, M_TOK, M_TOK, SP_, NBS_, 2, 0, 0, NB, 1,
                    Off{B_, (long long)M_TOK * 128, (long long)S_ * 8},
                    Off{B_, (long long)M_TOK * 128, (long long)S_ * 8},
                    Off{1, (long long)S_ * 8, 0}, Z0);
        // softmax in place on blocked fp16
        att_softmax_kernel<<<NB * S_, 64, 0, stream>>>(att_h, scale);
        // O = att @ v  (+residual into tok, fp32 row-major)
        launch_mfma(stream, att_h, vt_h, nullptr, tok, nullptr,
                    S_, DH_, SP_, NBS_, VROWS_, D_, 0, 0, 1, 0, NB, 1,
                    Off{1, (long long)S_ * 8, 0},
                    Off{B_, (long long)B_ * DH_ * 8, (long long)DH_ * 8},
                    Off{B_, 64, (long long)S_ * D_}, Z0);
        // LN2 -> blocked fp16
        ln_split_kernel<<<M_TOK, 256, 0, stream>>>(tok, h_h, ln2_g + l * D_, ln2_b + l * D_);
        // weights -> blocked transposed fp16
        tconv_kernel<<<dim3(MLP_ / 32, D_ / 32), 256, 0, stream>>>(
            w1 + (long long)l * D_ * MLP_, w1t, D_, MLP_);
        tconv_kernel<<<dim3(D_ / 32, MLP_ / 32), 256, 0, stream>>>(
            w2 + (long long)l * MLP_ * D_, w2t, MLP_, D_);
        // MLP1: gelu(h @ w1 + b1) -> g blocked fp16
        launch_mfma(stream, h_h, w1t, b1 + (long long)l * MLP_,
                    nullptr, g_h, M_TOK, MLP_, D_, M_TOK, MLP_, MLP_, M_TOK, 1, 0, 0, 1, 1,
                    Z0, Z0, Z0, Z0);
        // MLP2: tok += g @ w2 + b2  -- split-K x4: 1200 blocks, atomicAdd epilogue
        launch_mfma(stream, g_h, w2t, b2 + (long long)l * D_,
                    tok, nullptr, M_TOK, D_, MLP_, M_TOK, D_, D_, 0, 0, 1, 0, 4, 4,
                    Z0, Z0, Z0, Z0);
    }

    // head (fp32, tiny)
    launch_gemm(stream, tok, w_head, b_head, logits,
                B_, OUT_, D_, S_ * D_, OUT_, OUT_, 0, 0, 0, 1, Z0, Z0, Z0, Z0);
    head_softmax_kernel<<<B_, 256, 0, stream>>>(logits, out);
}

// Round 6
// 5129.928 us; speedup vs baseline: 2.3568x; 1.0380x over previous
//
#include <hip/hip_runtime.h>
#include <math.h>

// ---------------- dims ----------------
#define B_ 32
#define C_ 3
#define HW_ 224
#define NP_ 14
#define PS_ 16
#define S_ 197        // NP*NP + 1
#define SP_ 224       // S padded to multiple of 32 (K dim of AV)
#define D_ 768
#define NH_ 12
#define DH_ 64
#define L_ 12
#define MLP_ 3072
#define OUT_ 1000

#define BM 64
#define BN 64
#define BK 16

// blocked (K-octet-major) layouts: buf[k/8][rows][8] -> fully coalesced
// global_load_lds staging (lane i reads base + i*16B, 1KB burst/instruction).
#define OID(rows, r, k) ((((long long)((k) >> 3)) * (rows) + (r)) * 8 + ((k) & 7))

#define NBS_ (B_ * NH_ * S_)          // 75648 rows of att
#define VROWS_ (NH_ * B_ * DH_)       // 24576 rows of vt

typedef unsigned short u16;
typedef unsigned int u32;
typedef __attribute__((ext_vector_type(8))) _Float16 half8_t;
typedef __attribute__((ext_vector_type(4))) float f32x4;
typedef const __attribute__((address_space(1))) u16 gq_t;
typedef __attribute__((address_space(3))) u16 lq_t;

// ---------------- fp16 helpers ----------------
__device__ __forceinline__ u16 f2h(float x) {
    union { _Float16 h; u16 u; } c; c.h = (_Float16)x; return c.u;
}
__device__ __forceinline__ float h2f(u16 u) {
    union { _Float16 h; u16 u; } c; c.u = u; return (float)c.h;
}

// ================= fp16 MFMA GEMM (blocked operands, 3-deep counted-vmcnt pipeline) =================
// C = A @ B^T(stored blocked [K/8][rowsN][8]), fp16 inputs, fp32 accumulate.
// A is blocked [K/8][rowsM][8]; mplaneA/mplaneB = rows per k-octet plane.
// K-loop: 3 LDS buffers; loads stay in flight across barriers (s_waitcnt vmcnt(8),
// never 0 in steady state). Two raw s_barriers per step:
//   B1 after own-vmcnt wait  -> all waves' loads for buf cur landed
//   B2 after lgkmcnt(0)      -> all waves done READING buf cur (safe to restage)
// Per-z offsets: off = (z/div)*so + (z%div)*si (element offsets into blocked bufs).
// ksplit>1: blockIdx.z = K chunk; epilogue atomicAdd into C; bias only chunk 0.
// mode 0: C[row*ldc+col] = acc+bias (+C_old if accum); remap row=grow+grow/196+1
// mode 1: gelu(acc+bias) -> fp16 at OID(orows, grow, col)
// mode 2: (acc+bias)     -> fp16 at OID(orows, grow, col); zero-fills cols [N,ldc)
// mode 3: (acc+bias)     -> fp16 v^T: OID(orows, nn*DH_+col, ss)
__global__ __launch_bounds__(256) void mfma_gemm_kernel(
    const u16* __restrict__ Aq, const u16* __restrict__ Bq,
    const float* __restrict__ bias, float* __restrict__ C,
    u16* __restrict__ Oq,
    int M, int N, int K, int mplaneA, int mplaneB, int ldc, long long orows,
    int mode, int accum, int remap, int ksplit,
    int divA, long long sAo, long long sAi,
    int divB, long long sBo, long long sBi,
    int divC, long long sCo, long long sCi,
    int divBias, long long sBiaso, long long sBiasi)
{
    // chunk-major LDS: [buf][mat][k-octet][row][8 fp16] -> conflict-free b128 reads.
    __shared__ u16 lds[3][2][4][128][8];   // 48 KB, 3-deep

    int z = blockIdx.z;
    int kz = 0;
    if (ksplit > 1) { kz = z; z = 0; }
    long long aoff = (long long)(z / divA) * sAo + (long long)(z % divA) * sAi;
    long long boff = (long long)(z / divB) * sBo + (long long)(z % divB) * sBi;
    long long coff = (long long)(z / divC) * sCo + (long long)(z % divC) * sCi;
    long long biasoff = (long long)(z / divBias) * sBiaso + (long long)(z % divBias) * sBiasi;

    // ---- bijective XCD-chunked swizzle of the 2D grid (m204) ----
    int nwgx = gridDim.x;
    int nwg = nwgx * gridDim.y;
    int bid = blockIdx.y * nwgx + blockIdx.x;
    int xcd = bid & 7, lid = bid >> 3;
    int qq = nwg >> 3, rr8 = nwg & 7;
    int sw = ((xcd < rr8) ? xcd * (qq + 1) : rr8 * (qq + 1) + (xcd - rr8) * qq) + lid;
    int bx = sw % nwgx, by = sw / nwgx;

    int tid = threadIdx.x;
    int lane = tid & 63;
    int w = tid >> 6;                  // wave id 0..3
    int wm = (w >> 1) * 64, wn = (w & 1) * 64;
    int m0 = by * 128, n0 = bx * 128;
    int lm = lane & 15, qd = lane >> 4;

    // staging role: wave pair (w>>1) -> matrix, (w&1) -> row half
    int smat = w >> 1, shh = w & 1;
    const u16* src = smat ? (Bq + boff) : (Aq + aoff);
    int mp = smat ? mplaneB : mplaneA;
    int sbase = smat ? n0 : m0;
    int srmax = smat ? (N - 1) : (M - 1);
    int sr = sbase + shh * 64 + lane;
    if (sr > srmax) sr = srmax;

    int kc = K / ksplit;
    int kbeg = kz * kc;
    int nsteps = kc / 32;

    // stage one 128x32 tile pair; each wave issues 4 x 1KB coalesced bursts
    auto STAGE = [&](int buf, int k0) {
#pragma unroll
        for (int q = 0; q < 4; ++q) {
            const u16* gp = src + ((long long)((k0 >> 3) + q) * mp + sr) * 8;
            u16* lp = &lds[buf][smat][q][shh * 64][0];
            __builtin_amdgcn_global_load_lds((gq_t*)gp, (lq_t*)lp, 16, 0, 0);
        }
    };

    f32x4 acc[4][4];
#pragma unroll
    for (int i = 0; i < 4; ++i)
#pragma unroll
        for (int j = 0; j < 4; ++j)
            acc[i][j] = (f32x4){0.f, 0.f, 0.f, 0.f};

    // prologue: fill up to 3 buffers (12 loads/wave in flight)
    STAGE(0, kbeg);
    if (nsteps > 1) STAGE(1, kbeg + 32);
    if (nsteps > 2) STAGE(2, kbeg + 64);

    int cur = 0;
    for (int t = 0; t < nsteps; ++t) {
        int rem = nsteps - 1 - t;      // tiles in flight beyond current
        // wait for OWN 4 loads of buf cur (newer tiles stay in flight)
        if (rem >= 2)      asm volatile("s_waitcnt vmcnt(8)" ::: "memory");
        else if (rem == 1) asm volatile("s_waitcnt vmcnt(4)" ::: "memory");
        else               asm volatile("s_waitcnt vmcnt(0)" ::: "memory");
        __builtin_amdgcn_s_barrier();  // B1: all waves' buf-cur loads landed

        half8_t a[4], b[4];
#pragma unroll
        for (int i = 0; i < 4; ++i) {
            a[i] = *(const half8_t*)&lds[cur][0][qd][wm + i * 16 + lm][0];
            b[i] = *(const half8_t*)&lds[cur][1][qd][wn + i * 16 + lm][0];
        }
        asm volatile("s_waitcnt lgkmcnt(0)" ::: "memory");   // frags in regs
        __builtin_amdgcn_sched_barrier(0);
        __builtin_amdgcn_s_barrier();  // B2: all waves done reading buf cur

        if (t + 3 < nsteps) STAGE(cur, kbeg + (t + 3) * 32); // refill during MFMAs

#pragma unroll
        for (int i = 0; i < 4; ++i)
#pragma unroll
            for (int j = 0; j < 4; ++j)
                acc[i][j] = __builtin_amdgcn_mfma_f32_16x16x32_f16(a[i], b[j], acc[i][j], 0, 0, 0);

        cur = (cur == 2) ? 0 : cur + 1;
    }

    float* Cb = C ? C + coff : nullptr;
    u16* Ob = Oq ? Oq + coff : nullptr;
    const float* biasb = (bias && kz == 0) ? bias + biasoff : nullptr;

    // ---- epilogue: C/D layout col=lane&15, row=quad*4+reg ----
#pragma unroll
    for (int j = 0; j < 4; ++j) {
        int col = n0 + wn + j * 16 + lm;
        bool cok = col < N;
        float bv = (cok && biasb) ? biasb[col] : 0.f;
#pragma unroll
        for (int i = 0; i < 4; ++i) {
#pragma unroll
            for (int r = 0; r < 4; ++r) {
                int grow = m0 + wm + i * 16 + qd * 4 + r;
                if (grow >= M) continue;
                float v = acc[i][j][r] + bv;
                if (mode == 2) {
                    if (col >= ldc) continue;          // never cross plane range
                    if (!cok) v = 0.f;                 // zero-fill K padding
                    Ob[OID(orows, grow, col)] = f2h(v);
                } else if (mode == 3) {
                    if (!cok) continue;
                    int nn = grow / S_;
                    int ss = grow - nn * S_;
                    Ob[OID(orows, nn * DH_ + col, ss)] = f2h(v);
                } else if (mode == 1) {
                    if (!cok) continue;
                    v = 0.5f * v * (1.0f + erff(v * 0.70710678118654752f));
                    Ob[OID(orows, grow, col)] = f2h(v);
                } else {
                    if (!cok) continue;
                    int orow = remap ? (grow + grow / 196 + 1) : grow;
                    long long idx = (long long)orow * ldc + col;
                    if (ksplit > 1) {
                        atomicAdd(&Cb[idx], v);        // accum semantics, nondet order
                    } else {
                        if (accum) v += Cb[idx];
                        Cb[idx] = v;
                    }
                }
            }
        }
    }
}

// ---------------- transpose + fp16 convert of fp32 weights (blocked out) ----------------
// in:  W [K][N] fp32 row-major;  out: T blocked [K/8][N][8] fp16
__global__ __launch_bounds__(256) void tconv_kernel(const float* __restrict__ W,
                                                    u16* __restrict__ T,
                                                    int K, int N)
{
    __shared__ float t[32][33];
    int n0 = blockIdx.x * 32, k0 = blockIdx.y * 32;
    int tc = threadIdx.x & 31, tr = threadIdx.x >> 5;   // tr in 0..7
#pragma unroll
    for (int u = 0; u < 4; ++u) {
        int kk = tr + u * 8;
        t[kk][tc] = W[(long long)(k0 + kk) * N + n0 + tc];
    }
    __syncthreads();
#pragma unroll
    for (int u = 0; u < 4; ++u) {
        int nn = tr + u * 8;
        T[OID(N, n0 + nn, k0 + tc)] = f2h(t[tc][nn]);
    }
}

// ---------------- per-layer QKV weight prep (blocked fp16 out) ----------------
// wqk blocked per h: [8][128][8] (rows j=0..127: q|k, k=d);  wvt per h: [8][64][8]
__global__ void qkvprep_kernel(const float* __restrict__ wq, const float* __restrict__ wk,
                               const float* __restrict__ wv,
                               const float* __restrict__ bq, const float* __restrict__ bk,
                               u16* __restrict__ qkh,
                               u16* __restrict__ vth,
                               float* __restrict__ bqk)
{
    int idx = blockIdx.x * 256 + threadIdx.x;
    if (idx < NH_ * 128 * 64) {
        int d = idx & 63, j = (idx >> 6) & 127, h = idx >> 13;
        float v = (j < 64) ? wq[((h << 6) + d) * 64 + j] : wk[((h << 6) + d) * 64 + (j & 63)];
        qkh[(long long)h * 8192 + ((d >> 3) * 128 + j) * 8 + (d & 7)] = f2h(v);
        return;
    }
    int i2 = idx - NH_ * 128 * 64;
    if (i2 < NH_ * 64 * 64) {
        int d = i2 & 63, j = (i2 >> 6) & 63, h = i2 >> 12;
        vth[(long long)h * 4096 + ((d >> 3) * 64 + j) * 8 + (d & 7)] = f2h(wv[((h << 6) + d) * 64 + j]);
        return;
    }
    int i3 = i2 - NH_ * 64 * 64;
    if (i3 < NH_ * 128) {
        int j = i3 & 127, h = i3 >> 7;
        bqk[i3] = (j < 64) ? bq[(h << 6) + j] : bk[(h << 6) + (j & 63)];
    }
}

// ---------------- zero fill (u32) ----------------
__global__ void zfill_kernel(u32* __restrict__ p, long long n) {
    long long i = (long long)blockIdx.x * 256 + threadIdx.x;
    if (i < n) p[i] = 0u;
}

// ================= fp32 generic batched GEMM (head only) =================
__global__ __launch_bounds__(256) void gemm_kernel(
    const float* __restrict__ A, const float* __restrict__ Bm,
    const float* __restrict__ bias, float* __restrict__ C,
    int M, int N, int K, int lda, int ldb, int ldc,
    int transB, int act, int accum,
    int divA, long long sAo, long long sAi,
    int divB, long long sBo, long long sBi,
    int divC, long long sCo, long long sCi,
    int divBias, long long sBiaso, long long sBiasi)
{
    int z = blockIdx.z;
    const float* Ab = A + (long long)(z / divA) * sAo + (long long)(z % divA) * sAi;
    const float* Bb = Bm + (long long)(z / divB) * sBo + (long long)(z % divB) * sBi;
    float* Cb = C + (long long)(z / divC) * sCo + (long long)(z % divC) * sCi;
    const float* biasb = bias ? (bias + (long long)(z / divBias) * sBiaso + (long long)(z % divBias) * sBiasi)
                              : nullptr;

    __shared__ float As[BK][BM + 4];
    __shared__ float Bs[BK][BN + 4];

    int tid = threadIdx.x;
    int tx = tid & 15, ty = tid >> 4;
    int m0 = blockIdx.y * BM, n0 = blockIdx.x * BN;

    float acc[4][4] = {};

    for (int k0 = 0; k0 < K; k0 += BK) {
        {
            int row = tid >> 2;
            int c4 = (tid & 3) * 4;
            int gm = m0 + row;
#pragma unroll
            for (int u = 0; u < 4; ++u) {
                int gk = k0 + c4 + u;
                float v = 0.f;
                if (gm < M && gk < K) v = Ab[(long long)gm * lda + gk];
                As[c4 + u][row] = v;
            }
        }
        if (!transB) {
            int row = tid >> 4;
            int c4 = (tid & 15) * 4;
            int gk = k0 + row;
#pragma unroll
            for (int u = 0; u < 4; ++u) {
                int gn = n0 + c4 + u;
                float v = 0.f;
                if (gk < K && gn < N) v = Bb[(long long)gk * ldb + gn];
                Bs[row][c4 + u] = v;
            }
        } else {
            int row = tid >> 2;
            int c4 = (tid & 3) * 4;
            int gn = n0 + row;
#pragma unroll
            for (int u = 0; u < 4; ++u) {
                int gk = k0 + c4 + u;
                float v = 0.f;
                if (gn < N && gk < K) v = Bb[(long long)gn * ldb + gk];
                Bs[c4 + u][row] = v;
            }
        }
        __syncthreads();
#pragma unroll
        for (int kk = 0; kk < BK; ++kk) {
            float a[4], b[4];
#pragma unroll
            for (int i = 0; i < 4; ++i) a[i] = As[kk][ty * 4 + i];
#pragma unroll
            for (int j = 0; j < 4; ++j) b[j] = Bs[kk][tx * 4 + j];
#pragma unroll
            for (int i = 0; i < 4; ++i)
#pragma unroll
                for (int j = 0; j < 4; ++j)
                    acc[i][j] += a[i] * b[j];
        }
        __syncthreads();
    }

#pragma unroll
    for (int i = 0; i < 4; ++i) {
        int gm = m0 + ty * 4 + i;
        if (gm >= M) continue;
#pragma unroll
        for (int j = 0; j < 4; ++j) {
            int gn = n0 + tx * 4 + j;
            if (gn >= N) continue;
            float v = acc[i][j];
            if (biasb) v += biasb[gn];
            if (act == 1) v = 0.5f * v * (1.0f + erff(v * 0.70710678118654752f));
            long long idx = (long long)gm * ldc + gn;
            if (accum) v += Cb[idx];
            Cb[idx] = v;
        }
    }
}

// ---------------- positional embedding ----------------
__global__ void posemb_kernel(float* __restrict__ pos) {
    int idx = blockIdx.x * 256 + threadIdx.x;
    if (idx >= S_ * D_) return;
    int s = idx / D_, d = idx % D_;
    float jj = (float)(d & ~1);
    float freq = powf(10000.0f, jj / (float)D_);
    float arg = (float)s / freq;
    pos[idx] = (d & 1) ? cosf(arg) : sinf(arg);
}

// ---------------- patchify (blocked fp16 out) ----------------
__global__ void patchify_split_kernel(const float* __restrict__ x,
                                      u16* __restrict__ phi) {
    int idx = blockIdx.x * 256 + threadIdx.x;
    if (idx >= B_ * NP_ * NP_ * 768) return;
    int k = idx % 768;
    int row = idx / 768;                  // n*196 + p
    int p = row % (NP_ * NP_);
    int n = row / (NP_ * NP_);
    int c = k >> 8;
    int rem = k & 255;
    int a = rem >> 4;
    int b = rem & 15;
    int i = p / NP_, j = p % NP_;
    float v = x[(((long long)n * C_ + c) * HW_ + (i * PS_ + a)) * HW_ + (j * PS_ + b)];
    phi[OID(B_ * NP_ * NP_, row, k)] = f2h(v);
}

// ---------------- cls token + pos emb ----------------
__global__ void addpos_kernel(float* __restrict__ tok, const float* __restrict__ pos,
                              const float* __restrict__ cls) {
    int idx = blockIdx.x * 256 + threadIdx.x;
    if (idx >= B_ * S_ * D_) return;
    int r = idx % (S_ * D_);
    int s = r / D_, d = r % D_;
    if (s == 0) tok[idx] = cls[d] + pos[d];
    else tok[idx] += pos[r];
}

// ---------------- layernorm, blocked fp16 out ----------------
__global__ __launch_bounds__(256) void ln_split_kernel(const float* __restrict__ x,
                                                       u16* __restrict__ yh,
                                                       const float* __restrict__ g, const float* __restrict__ b) {
    int row = blockIdx.x;
    const float* xr = x + (long long)row * D_;
    int tid = threadIdx.x;
    float v[3];
    float s = 0.f;
#pragma unroll
    for (int u = 0; u < 3; ++u) { v[u] = xr[tid + 256 * u]; s += v[u]; }
    __shared__ float red[256];
    red[tid] = s; __syncthreads();
    for (int off = 128; off > 0; off >>= 1) { if (tid < off) red[tid] += red[tid + off]; __syncthreads(); }
    float mu = red[0] * (1.0f / D_);
    __syncthreads();
    float s2 = 0.f;
#pragma unroll
    for (int u = 0; u < 3; ++u) { float d = v[u] - mu; s2 += d * d; }
    red[tid] = s2; __syncthreads();
    for (int off = 128; off > 0; off >>= 1) { if (tid < off) red[tid] += red[tid + off]; __syncthreads(); }
    float rstd = rsqrtf(red[0] * (1.0f / D_) + 1e-5f);
#pragma unroll
    for (int u = 0; u < 3; ++u) {
        int d = tid + 256 * u;
        float yv = (v[u] - mu) * rstd * g[d] + b[d];
        yh[OID(B_ * S_, row, d)] = f2h(yv);
    }
}

// ---------------- attention softmax: in-place on blocked fp16 ----------------
__global__ __launch_bounds__(64) void att_softmax_kernel(u16* __restrict__ att, float scale) {
    long long rbase = (long long)blockIdx.x * 8;   // row enters OID as row*8
    int tid = threadIdx.x;
    float v[4];
    long long ix[4];
    float mx = -1e30f;
#pragma unroll
    for (int u = 0; u < 4; ++u) {
        int t = tid + 64 * u;
        ix[u] = (long long)(t >> 3) * (NBS_ * 8LL) + rbase + (t & 7);
        v[u] = (t < S_) ? h2f(att[ix[u]]) * scale : -1e30f;
        mx = fmaxf(mx, v[u]);
    }
    for (int off = 32; off > 0; off >>= 1) mx = fmaxf(mx, __shfl_xor(mx, off));
    float sum = 0.f;
#pragma unroll
    for (int u = 0; u < 4; ++u) { v[u] = expf(v[u] - mx); sum += v[u]; }
    for (int off = 32; off > 0; off >>= 1) sum += __shfl_xor(sum, off);
    float inv = 1.0f / sum;
#pragma unroll
    for (int u = 0; u < 4; ++u) {
        int t = tid + 64 * u;
        if (t < S_) att[ix[u]] = f2h(v[u] * inv);
    }
}

// ---------------- head softmax ----------------
__global__ __launch_bounds__(256) void head_softmax_kernel(const float* __restrict__ logits,
                                                           float* __restrict__ out) {
    int n = blockIdx.x;
    const float* p = logits + (long long)n * OUT_;
    int tid = threadIdx.x;
    float v[4];
    float mx = -1e30f;
#pragma unroll
    for (int u = 0; u < 4; ++u) {
        int idx = tid + 256 * u;
        v[u] = (idx < OUT_) ? p[idx] : -1e30f;
        mx = fmaxf(mx, v[u]);
    }
    __shared__ float red[256];
    red[tid] = mx; __syncthreads();
    for (int off = 128; off > 0; off >>= 1) { if (tid < off) red[tid] = fmaxf(red[tid], red[tid + off]); __syncthreads(); }
    mx = red[0];
    __syncthreads();
    float sum = 0.f;
#pragma unroll
    for (int u = 0; u < 4; ++u) { v[u] = expf(v[u] - mx); sum += v[u]; }
    red[tid] = sum; __syncthreads();
    for (int off = 128; off > 0; off >>= 1) { if (tid < off) red[tid] += red[tid + off]; __syncthreads(); }
    float inv = 1.0f / red[0];
#pragma unroll
    for (int u = 0; u < 4; ++u) {
        int idx = tid + 256 * u;
        if (idx < OUT_) out[(long long)n * OUT_ + idx] = v[u] * inv;
    }
}

// ---------------- host helpers ----------------
struct Off { int div; long long so, si; };
static const Off Z0 = {1, 0, 0};

static inline void launch_gemm(hipStream_t st, const float* A, const float* Bm, const float* bias,
                               float* C, int M, int N, int K, int lda, int ldb, int ldc,
                               int transB, int act, int accum, int batch,
                               Off a, Off b, Off c, Off bb) {
    dim3 grid((N + BN - 1) / BN, (M + BM - 1) / BM, batch);
    gemm_kernel<<<grid, dim3(256), 0, st>>>(A, Bm, bias, C, M, N, K, lda, ldb, ldc,
                                            transB, act, accum,
                                            a.div, a.so, a.si, b.div, b.so, b.si,
                                            c.div, c.so, c.si, bb.div, bb.so, bb.si);
}

static inline void launch_mfma(hipStream_t st,
                               const u16* Aq, const u16* Bq,
                               const float* bias, float* C, u16* Oq,
                               int M, int N, int K, int mplaneA, int mplaneB, int ldc, long long orows,
                               int mode, int accum, int remap, int batch, int ksplit,
                               Off a, Off b, Off c, Off bb) {
    dim3 grid((N + 127) / 128, (M + 127) / 128, batch);
    mfma_gemm_kernel<<<grid, dim3(256), 0, st>>>(Aq, Bq, bias, C, Oq,
                                                 M, N, K, mplaneA, mplaneB, ldc, orows,
                                                 mode, accum, remap, ksplit,
                                                 a.div, a.so, a.si, b.div, b.so, b.si,
                                                 c.div, c.so, c.si, bb.div, bb.so, bb.si);
}

extern "C" void kernel_launch(void* const* d_in, const int* in_sizes, int n_in,
                              void* d_out, int out_size, void* d_ws, size_t ws_size,
                              hipStream_t stream) {
    (void)in_sizes; (void)n_in; (void)out_size; (void)ws_size;
    const float* x        = (const float*)d_in[0];
    const float* w_embed  = (const float*)d_in[1];
    const float* b_embed  = (const float*)d_in[2];
    const float* cls_tok  = (const float*)d_in[3];
    const float* ln1_g    = (const float*)d_in[4];
    const float* ln1_b    = (const float*)d_in[5];
    const float* wq       = (const float*)d_in[6];
    const float* bq       = (const float*)d_in[7];
    const float* wk       = (const float*)d_in[8];
    const float* bk       = (const float*)d_in[9];
    const float* wv       = (const float*)d_in[10];
    const float* bv       = (const float*)d_in[11];
    const float* ln2_g    = (const float*)d_in[12];
    const float* ln2_b    = (const float*)d_in[13];
    const float* w1       = (const float*)d_in[14];
    const float* b1       = (const float*)d_in[15];
    const float* w2       = (const float*)d_in[16];
    const float* b2       = (const float*)d_in[17];
    const float* w_head   = (const float*)d_in[18];
    const float* b_head   = (const float*)d_in[19];
    float* out = (float*)d_out;
    char* wsb  = (char*)d_ws;

    const long long TOKSZ = (long long)B_ * S_ * D_;          // 4,841,472
    const int M_TOK = B_ * S_;                                 // 6304
    const int M_PAT = B_ * NP_ * NP_;                          // 6272
    const int NB = B_ * NH_;                                   // 384

    // ---- workspace carve (bytes, 256B aligned) ----
    auto alloc = [&](long long bytes) {
        char* p = wsb;
        wsb += (bytes + 255) & ~255LL;
        return p;
    };
    float* pos    = (float*)alloc((long long)S_ * D_ * 4);
    float* tok    = (float*)alloc(TOKSZ * 4);
    u16*   h_h    = (u16*)alloc(TOKSZ * 2);                    // LN out, blocked [96][M_TOK][8]
    u16*   qk_h   = (u16*)alloc((long long)NH_ * M_TOK * 128 * 2);   // per h: [16][M_TOK][8]
    u16*   vt_h   = (u16*)alloc((long long)SP_ * VROWS_ * 2);  // [28][VROWS][8]
    u16*   w1t    = (u16*)alloc((long long)MLP_ * D_ * 2);     // blocked [96][MLP][8]; wet pre-loop
    u16*   w2t    = (u16*)alloc((long long)D_ * MLP_ * 2);     // blocked [384][768][8]
    u16*   wqk    = (u16*)alloc((long long)NH_ * 128 * 64 * 2);
    u16*   wvt    = (u16*)alloc((long long)NH_ * 64 * 64 * 2);
    float* bqk_f  = (float*)alloc((long long)NH_ * 128 * 4);
    // big region: max(att 33.9MB, gelu 38.7MB, patches 9.6MB)
    char* bigreg  = alloc((long long)M_TOK * MLP_ * 2);
    u16*   att_h  = (u16*)bigreg;                              // blocked [28][NBS_][8]
    u16*   g_h    = (u16*)bigreg;                              // blocked [384][M_TOK][8]
    u16*   p_h    = (u16*)bigreg;                              // blocked [96][M_PAT][8] pre-loop
    float* logits = (float*)alloc((long long)B_ * OUT_ * 4);

    // ---- embed path ----
    posemb_kernel<<<(S_ * D_ + 255) / 256, 256, 0, stream>>>(pos);
    patchify_split_kernel<<<(M_PAT * 768 + 255) / 256, 256, 0, stream>>>(x, p_h);
    tconv_kernel<<<dim3(768 / 32, 768 / 32), 256, 0, stream>>>(w_embed, w1t, 768, 768);
    launch_mfma(stream, p_h, w1t, b_embed, tok, nullptr,
                M_PAT, D_, 768, M_PAT, 768, D_, 0, 0, 0, 1, 1, 1, Z0, Z0, Z0, Z0);
    addpos_kernel<<<((int)TOKSZ + 255) / 256, 256, 0, stream>>>(tok, pos, cls_tok);
    // zero v^T (pads kv in [197,224) must stay 0; live region rewritten each layer)
    {
        long long n32 = (long long)SP_ * VROWS_ / 2;           // u16 count / 2
        zfill_kernel<<<(int)((n32 + 255) / 256), 256, 0, stream>>>((u32*)vt_h, n32);
    }

    const float scale = 0.125f;
    const int QKVPREP_N = NH_ * 128 * 64 + NH_ * 64 * 64 + NH_ * 128;

    for (int l = 0; l < L_; ++l) {
        // LN1 -> blocked fp16
        ln_split_kernel<<<M_TOK, 256, 0, stream>>>(tok, h_h, ln1_g + l * D_, ln1_b + l * D_);
        // per-layer QKV weight prep (blocked fp16)
        qkvprep_kernel<<<(QKVPREP_N + 255) / 256, 256, 0, stream>>>(
            wq + (long long)l * NH_ * DH_ * DH_, wk + (long long)l * NH_ * DH_ * DH_,
            wv + (long long)l * NH_ * DH_ * DH_,
            bq + (long long)l * NH_ * DH_, bk + (long long)l * NH_ * DH_,
            wqk, wvt, bqk_f);
        // Q|K: per-head GEMM; A = h planes [8z..8z+8); out blocked per h
        launch_mfma(stream, h_h, wqk, bqk_f, nullptr, qk_h,
                    M_TOK, 128, 64, M_TOK, 128, 128, M_TOK, 2, 0, 0, NH_, 1,
                    Off{1, (long long)M_TOK * 64, 0}, Off{1, 8192, 0},
                    Off{1, (long long)M_TOK * 128, 0}, Off{1, 128, 0});
        // V: per-head GEMM, out blocked v^T [28][VROWS][8]
        launch_mfma(stream, h_h, wvt, bv + (long long)l * NH_ * DH_, nullptr, vt_h,
                    M_TOK, 64, 64, M_TOK, 64, SP_, VROWS_, 3, 0, 0, NH_, 1,
                    Off{1, (long long)M_TOK * 64, 0}, Off{1, 4096, 0},
                    Off{1, (long long)B_ * DH_ * 8, 0}, Off{1, 64, 0});
        // scores = q @ k^T per (h,n): A = q planes, B = k planes (plane 8 base);
        // out blocked att, cols [197,224) zero-filled
        launch_mfma(stream, qk_h, qk_h + (long long)M_TOK * 64, nullptr, nullptr, att_h,
                    S_, S_, 64, M_TOK, M_TOK, SP_, NBS_, 2, 0, 0, NB, 1,
                    Off{B_, (long long)M_TOK * 128, (long long)S_ * 8},
                    Off{B_, (long long)M_TOK * 128, (long long)S_ * 8},
                    Off{1, (long long)S_ * 8, 0}, Z0);
        // softmax in place on blocked fp16
        att_softmax_kernel<<<NB * S_, 64, 0, stream>>>(att_h, scale);
        // O = att @ v  (+residual into tok, fp32 row-major)
        launch_mfma(stream, att_h, vt_h, nullptr, tok, nullptr,
                    S_, DH_, SP_, NBS_, VROWS_, D_, 0, 0, 1, 0, NB, 1,
                    Off{1, (long long)S_ * 8, 0},
                    Off{B_, (long long)B_ * DH_ * 8, (long long)DH_ * 8},
                    Off{B_, 64, (long long)S_ * D_}, Z0);
        // LN2 -> blocked fp16
        ln_split_kernel<<<M_TOK, 256, 0, stream>>>(tok, h_h, ln2_g + l * D_, ln2_b + l * D_);
        // weights -> blocked transposed fp16
        tconv_kernel<<<dim3(MLP_ / 32, D_ / 32), 256, 0, stream>>>(
            w1 + (long long)l * D_ * MLP_, w1t, D_, MLP_);
        tconv_kernel<<<dim3(D_ / 32, MLP_ / 32), 256, 0, stream>>>(
            w2 + (long long)l * MLP_ * D_, w2t, MLP_, D_);
        // MLP1: gelu(h @ w1 + b1) -> g blocked fp16
        launch_mfma(stream, h_h, w1t, b1 + (long long)l * MLP_,
                    nullptr, g_h, M_TOK, MLP_, D_, M_TOK, MLP_, MLP_, M_TOK, 1, 0, 0, 1, 1,
                    Z0, Z0, Z0, Z0);
        // MLP2: tok += g @ w2 + b2  -- split-K x4: 1200 blocks, atomicAdd epilogue
        launch_mfma(stream, g_h, w2t, b2 + (long long)l * D_,
                    tok, nullptr, M_TOK, D_, MLP_, M_TOK, D_, D_, 0, 0, 1, 0, 4, 4,
                    Z0, Z0, Z0, Z0);
    }

    // head (fp32, tiny)
    launch_gemm(stream, tok, w_head, b_head, logits,
                B_, OUT_, D_, S_ * D_, OUT_, OUT_, 0, 0, 0, 1, Z0, Z0, Z0, Z0);
    head_softmax_kernel<<<B_, 256, 0, stream>>>(logits, out);
}